// Round 4
// baseline (2337.943 us; speedup 1.0000x reference)
//
#include <hip/hip_runtime.h>
#include <hip/hip_bf16.h>

#define B_ 4
#define S_ 512
#define D_ 512
#define I_ 1024
#define C_ 32
#define NC_ 16

// ---- ws layout (float offsets) ----
#define KBUF (B_*S_*D_)
#define STSZ (B_*I_*D_)
#define HSZ  (B_*I_*C_)
#define DOSZ (B_*C_*D_)
#define OFF_K    0
#define OFF_V    (OFF_K + KBUF)
#define OFF_Q    (OFF_V + KBUF)
#define OFF_TH   (OFF_Q + KBUF)
#define OFF_AL   (OFF_TH + B_*S_)
#define OFF_ET   (OFF_AL + B_*S_)
#define OFF_KN2  (OFF_ET + B_*S_)
#define OFF_SLN  (OFF_KN2 + B_*S_)
#define OFF_MLN  (OFF_SLN + B_*D_)
#define OFF_H2   (OFF_MLN + B_*D_)
#define OFF_Z1   (OFF_H2 + 2*HSZ)
#define OFF_DHP  (OFF_Z1 + HSZ)
#define OFF_DO   (OFF_DHP + HSZ)
#define OFF_DLN  (OFF_DO + DOSZ)
#define OFF_OB   (OFF_DLN + DOSZ)
#define OFF_SLAB (OFF_OB + DOSZ)
#define SLABSTR  256
#define OFF_TICK (OFF_SLAB + NC_*B_*SLABSTR)
#define OFF_TK2  (OFF_TICK + 64)             // tkA[64] + tkB[64] ints
#define OFF_FLAG (OFF_TK2 + 128)
#define OFF_ORET (OFF_FLAG + 16)
#define OFF_BST  (OFF_ORET + KBUF)     // bf16 states start here (ushort*)
// bf16 state arrays (ushort element offsets within bst):
//   BSW1 = 0, BMW1 = STSZ, BSW2 = 2*STSZ, BMW2 = 3*STSZ
#define OFF_KBFf (OFF_BST + 2*STSZ)          // kbf[b][s][d] bf16 (KBUF ushorts)
#define OFF_KBTf (OFF_KBFf + KBUF/2)         // kbt[b][d][s] bf16 (KBUF ushorts)
#define OFF_HIT  (OFF_KBTf + KBUF/2)         // h [buf][b][i][t] bf16
#define OFF_HTI  (OFF_HIT + HSZ)             // h [buf][b][t][i] bf16
#define OFF_DOB  (OFF_HTI + HSZ)             // do [b][t][d] bf16
#define OFF_DOT  (OFF_DOB + DOSZ/2)          // do [b][d][t] bf16
// aliases (temporally disjoint):
//   xbf (bf16 x, pre-loop)        -> OFF_ORET lower half
//   qbf (bf16 q, from p1b)        -> OFF_ORET upper half (until r2 writes oret)
//   wbf (bf16 wk/wv/wq, pre-loop) -> OFF_KBFf region (tr_k overwrites after p1a)
//   hqb (bf16 hq, post-loop)      -> OFF_K region (k f32 dead after loop)

typedef __attribute__((ext_vector_type(8))) short s8v;    // 8 bf16 in 4 VGPR
typedef __attribute__((ext_vector_type(4))) float f4v;    // mfma C/D

__device__ __forceinline__ float bf2f(__hip_bfloat16 v){ return __bfloat162float(v); }
__device__ __forceinline__ float bfu2f(unsigned short u){ return __uint_as_float(((unsigned)u)<<16); }
__device__ __forceinline__ unsigned short f2bfu(float f){
  unsigned x = __float_as_uint(f);
  return (unsigned short)((x + 0x7FFFu + ((x>>16)&1u)) >> 16);
}
__device__ __forceinline__ float4 u42f4(ushort4 u){
  float4 r; r.x=bfu2f(u.x); r.y=bfu2f(u.y); r.z=bfu2f(u.z); r.w=bfu2f(u.w); return r;
}
__device__ __forceinline__ ushort4 f42u4(float4 v){
  ushort4 r; r.x=f2bfu(v.x); r.y=f2bfu(v.y); r.z=f2bfu(v.z); r.w=f2bfu(v.w); return r;
}
__device__ __forceinline__ float ldin(const void* p, size_t i, int f){
  return f ? ((const float*)p)[i] : bf2f(((const __hip_bfloat16*)p)[i]);
}
__device__ __forceinline__ float4 ld4g(const void* p, size_t i, int f){
  if(f) return ((const float4*)p)[i>>2];
  return u42f4(((const ushort4*)p)[i>>2]);
}
__device__ __forceinline__ void unp8(uint4 u, float* f){
  f[0]=bfu2f((unsigned short)(u.x&0xffffu)); f[1]=bfu2f((unsigned short)(u.x>>16));
  f[2]=bfu2f((unsigned short)(u.y&0xffffu)); f[3]=bfu2f((unsigned short)(u.y>>16));
  f[4]=bfu2f((unsigned short)(u.z&0xffffu)); f[5]=bfu2f((unsigned short)(u.z>>16));
  f[6]=bfu2f((unsigned short)(u.w&0xffffu)); f[7]=bfu2f((unsigned short)(u.w>>16));
}
__device__ __forceinline__ uint4 pck8(const float* f){
  uint4 u;
  u.x = (unsigned)f2bfu(f[0]) | ((unsigned)f2bfu(f[1])<<16);
  u.y = (unsigned)f2bfu(f[2]) | ((unsigned)f2bfu(f[3])<<16);
  u.z = (unsigned)f2bfu(f[4]) | ((unsigned)f2bfu(f[5])<<16);
  u.w = (unsigned)f2bfu(f[6]) | ((unsigned)f2bfu(f[7])<<16);
  return u;
}

__device__ __forceinline__ float blockReduceSum(float v, float* sm){
  #pragma unroll
  for(int o=32;o>0;o>>=1) v += __shfl_down(v,o,64);
  int wid = threadIdx.x>>6, lane = threadIdx.x&63;
  __syncthreads();
  if(lane==0) sm[wid]=v;
  __syncthreads();
  return sm[0]+sm[1]+sm[2]+sm[3];
}

// ---------------- D0: runtime input-dtype detection ----------------
__global__ void d0_detect(const void* __restrict__ x, float* __restrict__ ws){
  __shared__ int cnt;
  if(threadIdx.x==0) cnt=0;
  __syncthreads();
  unsigned w = ((const unsigned*)x)[(size_t)threadIdx.x*931 + 17];
  int e = (w>>7)&0xFF;
  if(e>=110 && e<=140) atomicAdd(&cnt,1);
  __syncthreads();
  if(threadIdx.x==0) ((int*)(ws+OFF_FLAG))[0] = (cnt<32) ? 1 : 0;  // 1 => f32 inputs
}

// ---------------- P0: init states / slabs / ticks ----------------
__global__ void p0_init(float* __restrict__ ws, const void* __restrict__ w1,
                        const void* __restrict__ w2, const void* __restrict__ ln){
  int f = ((const int*)(ws+OFF_FLAG))[0];
  unsigned short* bst = (unsigned short*)(ws + OFF_BST);
  size_t id = (size_t)blockIdx.x*blockDim.x + threadIdx.x;
  size_t stride = (size_t)gridDim.x*blockDim.x;
  ushort4 z4 = {0,0,0,0};
  for(size_t t4=id; t4<(size_t)(STSZ/4); t4+=stride){
    size_t e4 = t4 % (size_t)(I_*D_/4);
    *(ushort4*)(bst + (size_t)STSZ + t4*4)   = f42u4(ld4g(w1, e4*4, f));  // BMW1
    *(ushort4*)(bst + (size_t)3*STSZ + t4*4) = f42u4(ld4g(w2, e4*4, f));  // BMW2
    *(ushort4*)(bst + t4*4) = z4;                                          // BSW1
    *(ushort4*)(bst + (size_t)2*STSZ + t4*4) = z4;                         // BSW2
  }
  for(size_t t=id; t<(size_t)(B_*D_); t+=stride){
    ws[OFF_MLN+t] = ldin(ln,t % D_,f);
    ws[OFF_SLN+t] = 0.f;
  }
  for(size_t t=id; t<(size_t)(NC_*B_*SLABSTR); t+=stride) ws[OFF_SLAB+t]=0.f;
  int* tick = (int*)(ws + OFF_TICK);
  for(size_t t=id; t<192; t+=stride) tick[t]=0;   // TICK(64) + TK2(128)
}

// ---------------- CVT_IN: x, wk/wv/wq -> bf16 ----------------
__global__ void __launch_bounds__(256) cvt_in(const void* __restrict__ x,
                    const void* __restrict__ wk, const void* __restrict__ wv,
                    const void* __restrict__ wq, float* __restrict__ ws){
  int f = ((const int*)(ws+OFF_FLAG))[0];
  unsigned short* xbf = (unsigned short*)(ws + OFF_ORET);
  unsigned short* wbf = (unsigned short*)(ws + OFF_KBFf);
  size_t id = (size_t)blockIdx.x*blockDim.x + threadIdx.x;
  size_t stride = (size_t)gridDim.x*blockDim.x;
  for(size_t t4=id; t4<(size_t)(KBUF/4); t4+=stride)
    *(ushort4*)(xbf + t4*4) = f42u4(ld4g(x, t4*4, f));
  for(size_t t4=id; t4<(size_t)(3*D_*D_/4); t4+=stride){
    int pid = (int)(t4 / (D_*D_/4));
    size_t e4 = t4 % (size_t)(D_*D_/4);
    const void* W = (pid==0)?wk:((pid==1)?wv:wq);
    *(ushort4*)(wbf + t4*4) = f42u4(ld4g(W, e4*4, f));
  }
}

// ---------------- P1a (MFMA): k,v,q = silu(x@W^T) ----------------
__global__ void __launch_bounds__(256) p1a(float* __restrict__ ws){
  const unsigned short* xbf = (const unsigned short*)(ws + OFF_ORET);
  const unsigned short* wbf = (const unsigned short*)(ws + OFF_KBFf);
  int pid = blockIdx.z;
  float* outp = ws + ((pid==0)?OFF_K:((pid==1)?OFF_V:OFF_Q));
  const unsigned short* W = wbf + (size_t)pid*D_*D_;
  int r0 = blockIdx.x*64, j0 = blockIdx.y*64;
  int w = threadIdx.x>>6, lane = threadIdx.x&63;
  int col = lane&15, lg = lane>>4;
  f4v acc[4] = {{0,0,0,0},{0,0,0,0},{0,0,0,0},{0,0,0,0}};
  for(int k0=0;k0<512;k0+=32){
    s8v bB = __builtin_bit_cast(s8v, *(const uint4*)(W + (size_t)(j0 + w*16 + col)*512 + k0 + lg*8));
    #pragma unroll
    for(int rg=0;rg<4;rg++){
      s8v aA = __builtin_bit_cast(s8v, *(const uint4*)(xbf + (size_t)(r0 + rg*16 + col)*512 + k0 + lg*8));
      acc[rg] = __builtin_amdgcn_mfma_f32_16x16x32_bf16(aA, bB, acc[rg], 0,0,0);
    }
  }
  #pragma unroll
  for(int rg=0;rg<4;rg++)
    #pragma unroll
    for(int j=0;j<4;j++){
      float z = acc[rg][j];
      outp[(size_t)(r0 + rg*16 + lg*4 + j)*512 + j0 + w*16 + col] = z/(1.f+expf(-z));
    }
}

// ---------------- P1b: rms(k),rms(q)(+bf16 q), |k|^2, gates ----------------
__global__ void __launch_bounds__(256) p1b(const void* __restrict__ x,
                    const void* __restrict__ kn,
                    const void* __restrict__ qn,
                    const void* __restrict__ aw,
                    const void* __restrict__ tw,
                    const void* __restrict__ ew,
                    float* __restrict__ ws){
  int f = ((const int*)(ws+OFF_FLAG))[0];
  int tok = blockIdx.x; int tid = threadIdx.x;
  __shared__ float sm[8];
  float* krow = ws + OFF_K + (size_t)tok*512;
  float* qrow = ws + OFF_Q + (size_t)tok*512;
  float a = krow[tid], b = krow[tid+256];
  float ss = blockReduceSum(a*a+b*b, sm);
  float n = rsqrtf(ss*(1.f/512.f) + 1e-6f);
  float k1v = a*n*ldin(kn,tid,f);
  float k2v = b*n*ldin(kn,tid+256,f);
  krow[tid]=k1v; krow[tid+256]=k2v;
  float kn2 = blockReduceSum(k1v*k1v+k2v*k2v, sm);
  if(tid==0) ws[OFF_KN2+tok]=kn2;
  a = qrow[tid]; b = qrow[tid+256];
  ss = blockReduceSum(a*a+b*b, sm);
  n = rsqrtf(ss*(1.f/512.f)+1e-6f);
  float q1 = a*n*ldin(qn,tid,f);
  float q2 = b*n*ldin(qn,tid+256,f);
  qrow[tid]=q1; qrow[tid+256]=q2;
  unsigned short* qbf = (unsigned short*)(ws + OFF_ORET + KBUF/2);
  qbf[(size_t)tok*512+tid]     = f2bfu(q1);
  qbf[(size_t)tok*512+tid+256] = f2bfu(q2);
  float x1=ldin(x,(size_t)tok*512+tid,f), x2=ldin(x,(size_t)tok*512+tid+256,f);
  float td = blockReduceSum(x1*ldin(tw,tid,f) + x2*ldin(tw,tid+256,f), sm);
  float ad = blockReduceSum(x1*ldin(aw,tid,f) + x2*ldin(aw,tid+256,f), sm);
  float ed = blockReduceSum(x1*ldin(ew,tid,f) + x2*ldin(ew,tid+256,f), sm);
  if(tid==0){
    ws[OFF_TH+tok] = 0.01f/(1.f+expf(-td));
    ws[OFF_AL+tok] = 1.f/(1.f+expf(-ad));
    ws[OFF_ET+tok] = 1.f/(1.f+expf(-ed));
  }
}

// ---------------- TRK: snapshot normalized K as bf16, both orientations ----------------
__global__ void __launch_bounds__(256) tr_k(float* __restrict__ ws){
  unsigned short* kbf = (unsigned short*)(ws + OFF_KBFf);
  unsigned short* kbt = (unsigned short*)(ws + OFF_KBTf);
  int b = blockIdx.z, st = blockIdx.y, dt = blockIdx.x;
  int s0 = st*64, d0 = dt*64;
  __shared__ unsigned short t[64][72];
  int tid = threadIdx.x;
  #pragma unroll
  for(int q=0;q<4;q++){
    int idx = tid + q*256; int r = idx>>4, cq = idx&15;
    float4 v = *(const float4*)(ws + OFF_K + ((size_t)(b*512 + s0 + r))*512 + d0 + cq*4);
    ushort4 u; u.x=f2bfu(v.x); u.y=f2bfu(v.y); u.z=f2bfu(v.z); u.w=f2bfu(v.w);
    *(ushort4*)&t[r][cq*4] = u;
    *(ushort4*)(kbf + ((size_t)(b*512 + s0 + r))*512 + d0 + cq*4) = u;
  }
  __syncthreads();
  #pragma unroll
  for(int q=0;q<4;q++){
    int idx = tid + q*256; int d = idx>>4, sq = idx&15;
    ushort4 u; u.x=t[sq*4+0][d]; u.y=t[sq*4+1][d]; u.z=t[sq*4+2][d]; u.w=t[sq*4+3][d];
    *(ushort4*)(kbt + ((size_t)(b*512 + d0 + d))*512 + s0 + sq*4) = u;
  }
}

// ---------------- FUSED12: k1 (blocks 0..64) + k2 (blocks 65..96) ----------------
__global__ void __launch_bounds__(256,2) fused12(float* __restrict__ ws, int c){
  unsigned short* bsw1 = (unsigned short*)(ws + OFF_BST);
  unsigned short* bmw1 = bsw1 + STSZ;
  unsigned short* bsw2 = bsw1 + (size_t)2*STSZ;
  unsigned short* bmw2 = bsw1 + (size_t)3*STSZ;
  const unsigned short* kbf = (const unsigned short*)(ws + OFF_KBFf);
  const unsigned short* kbt = (const unsigned short*)(ws + OFF_KBTf);
  int b = blockIdx.y, bx = blockIdx.x, tid = threadIdx.x;
  int* tkA = (int*)(ws + OFF_TK2);
  __shared__ float sE[32], sC[32], scal[3];
  __shared__ __align__(16) float gbf[4][2][16][36];
  __shared__ __align__(16) unsigned short ztile[4][16][40];
  __shared__ __align__(16) float xred[4][16][32];
  __shared__ float hredL[32];
  if(c>0){
    const float* slab = ws + OFF_SLAB + ((long)(c-1)*B_ + b)*SLABSTR;
    if(tid<32){ sE[tid]=slab[128+tid]; sC[tid]=slab[160+tid]; }
    if(tid>=32 && tid<35) scal[tid-32]=slab[192+(tid-32)];
  }
  __syncthreads();
  float PE = c>0? scal[0]:1.f, PB = c>0? scal[1]:1.f, Q = c>0? scal[2]:0.f;
  int w = tid>>6, lane = tid&63;
  int col = lane&15, lg = lane>>4;
  int rr = lane>>2, c0 = (lane&3)*8;
  if(bx==64){
    if(c>0){
      for(int d=tid; d<512; d+=256){
        float gE=0,gC=0;
        for(int u=0;u<32;u++){
          float dl = ws[OFF_DLN + ((size_t)(b*32+u))*512 + d];
          gE += sE[u]*dl; gC += sC[u]*dl;
        }
        size_t ix = OFF_SLN + (size_t)b*512 + d;
        float sv=ws[ix], mv=ws[ix + (OFF_MLN-OFF_SLN)];
        ws[ix] = PE*sv - gE;
        ws[ix + (OFF_MLN-OFF_SLN)] = PB*mv + Q*sv - gC;
      }
    }
    return;
  }
  if(bx<64){
    // ---------------- k1 i-tile ----------------
    int i0 = bx*16;
    s8v aE = {}, aC = {};
    if(c>0){
      const float* dp = ws + OFF_DHP + ((size_t)(b*I_ + i0 + col))*32 + lg*8;
      float4 dv0 = *(const float4*)dp;
      float4 dv1 = *(const float4*)(dp+4);
      float dv[8] = {dv0.x,dv0.y,dv0.z,dv0.w,dv1.x,dv1.y,dv1.z,dv1.w};
      #pragma unroll
      for(int j=0;j<8;j++){
        aE[j] = (short)f2bfu(sE[lg*8+j]*dv[j]);
        aC[j] = (short)f2bfu(sC[lg*8+j]*dv[j]);
      }
    }
    f4v zacc0 = {0.f,0.f,0.f,0.f}, zacc1 = {0.f,0.f,0.f,0.f};
    const int d0w = w*128;
    const size_t srowbase = ((size_t)(b*I_ + i0))*512;
    const size_t kprow = (size_t)(c-1)*32;
    for(int sl=0; sl<4; sl++){
      int dbase = d0w + sl*32;
      size_t gaddr = srowbase + (size_t)rr*512 + dbase + c0;
      if(c>0){
        #pragma unroll
        for(int t2=0;t2<2;t2++){
          int dt = dbase + t2*16;
          const unsigned short* kp = kbt + ((size_t)(b*512 + dt + col))*512 + kprow + lg*8;
          s8v kB = __builtin_bit_cast(s8v, *(const uint4*)kp);
          f4v zero4 = {0.f,0.f,0.f,0.f};
          f4v gE4 = __builtin_amdgcn_mfma_f32_16x16x32_bf16(aE, kB, zero4, 0,0,0);
          f4v gC4 = __builtin_amdgcn_mfma_f32_16x16x32_bf16(aC, kB, zero4, 0,0,0);
          #pragma unroll
          for(int j=0;j<4;j++){
            gbf[w][0][lg*4+j][t2*16+col] = gE4[j];
            gbf[w][1][lg*4+j][t2*16+col] = gC4[j];
          }
        }
        uint4 su = *(uint4*)(bsw1 + gaddr);
        uint4 mu = *(uint4*)(bmw1 + gaddr);
        float s8[8], m8[8];
        unp8(su, s8); unp8(mu, m8);
        float ns[8], nmv[8];
        #pragma unroll
        for(int j=0;j<8;j++){
          float ge = gbf[w][0][rr][c0+j];
          float gc = gbf[w][1][rr][c0+j];
          ns[j]  = PE*s8[j] - ge;
          nmv[j] = PB*m8[j] + Q*s8[j] - gc;
        }
        *(uint4*)(bsw1 + gaddr) = pck8(ns);
        uint4 nmu = pck8(nmv);
        *(uint4*)(bmw1 + gaddr) = nmu;
        *(uint4*)&ztile[w][rr][c0] = nmu;
      } else {
        uint4 mu = *(uint4*)(bmw1 + gaddr);
        *(uint4*)&ztile[w][rr][c0] = mu;
      }
      if(c<16){
        s8v mA = __builtin_bit_cast(s8v, *(const uint4*)&ztile[w][col][lg*8]);
        const unsigned short* kc0 = kbf + ((size_t)(b*512 + c*32 + col))*512 + dbase + lg*8;
        s8v kB0 = __builtin_bit_cast(s8v, *(const uint4*)kc0);
        s8v kB1 = __builtin_bit_cast(s8v, *(const uint4*)(kc0 + (size_t)16*512));
        zacc0 = __builtin_amdgcn_mfma_f32_16x16x32_bf16(mA, kB0, zacc0, 0,0,0);
        zacc1 = __builtin_amdgcn_mfma_f32_16x16x32_bf16(mA, kB1, zacc1, 0,0,0);
      }
    }
    if(c<16){
      #pragma unroll
      for(int j=0;j<4;j++){
        xred[w][lg*4+j][col]    = zacc0[j];
        xred[w][lg*4+j][16+col] = zacc1[j];
      }
      if(tid<32) hredL[tid]=0.f;
      __syncthreads();
      unsigned short* hit = (unsigned short*)(ws + OFF_HIT) + (size_t)(c&1)*HSZ;
      unsigned short* hti = (unsigned short*)(ws + OFF_HTI) + (size_t)(c&1)*HSZ;
      #pragma unroll
      for(int e=0;e<2;e++){
        int idx = tid*2+e; int row = idx>>5, t = idx&31;
        float z = xred[0][row][t]+xred[1][row][t]+xred[2][row][t]+xred[3][row][t];
        size_t zb = ((size_t)(b*I_ + i0 + row))*32 + t;
        ws[OFF_Z1+zb] = z;
        float h = z/(1.f+expf(-z));
        unsigned short hb = f2bfu(h);
        hit[zb] = hb;
        hti[((size_t)(b*C_+t))*I_ + i0 + row] = hb;
        atomicAdd(&hredL[t], h*h);
      }
      __syncthreads();
      if(tid<32) atomicAdd(ws + OFF_SLAB + ((size_t)c*B_ + b)*SLABSTR + tid, hredL[tid]);
      // release: h visible device-wide, then tick
      __threadfence();
      __syncthreads();
      if(tid==0) atomicAdd(&tkA[c*B_+b], 1);
    }
    return;
  }
  // ---------------- k2 path (bx 65..96) ----------------
  int d0 = (bx-65)*16;
  const unsigned short* hitp = (const unsigned short*)(ws + OFF_HIT) + (size_t)((c-1)&1)*HSZ;
  const unsigned short* htic = (const unsigned short*)(ws + OFF_HTI) + (size_t)(c&1)*HSZ;
  const unsigned short* dotb = (const unsigned short*)(ws + OFF_DOT);
  const size_t srowbase = ((size_t)(b*D_ + d0))*1024;
  if(c>0){
    // phase G: W2 state update with prev-chunk grads (overlaps k1 blocks)
    s8v aE = {}, aC = {};
    {
      const unsigned short* dp = dotb + ((size_t)(b*D_ + d0 + col))*32 + lg*8;
      float dv[8]; unp8(*(const uint4*)dp, dv);
      #pragma unroll
      for(int j=0;j<8;j++){
        aE[j] = (short)f2bfu(sE[lg*8+j]*dv[j]);
        aC[j] = (short)f2bfu(sC[lg*8+j]*dv[j]);
      }
    }
    size_t ga0 = srowbase + (size_t)rr*1024 + w*256 + c0;
    uint4 su = *(uint4*)(bsw2 + ga0);
    uint4 mu = *(uint4*)(bmw2 + ga0);
    uint4 svn = su, mvn = mu;
    for(int sl=0; sl<8; sl++){
      int ibase = w*256 + sl*32;
      size_t gaddr = srowbase + (size_t)rr*1024 + ibase + c0;
      if(sl<7){
        svn = *(uint4*)(bsw2 + gaddr + 32);
        mvn = *(uint4*)(bmw2 + gaddr + 32);
      }
      #pragma unroll
      for(int t2=0;t2<2;t2++){
        const unsigned short* hp = hitp + ((size_t)(b*I_ + ibase + t2*16 + col))*32 + lg*8;
        s8v hB = __builtin_bit_cast(s8v, *(const uint4*)hp);
        f4v zero4 = {0.f,0.f,0.f,0.f};
        f4v gE4 = __builtin_amdgcn_mfma_f32_16x16x32_bf16(aE, hB, zero4, 0,0,0);
        f4v gC4 = __builtin_amdgcn_mfma_f32_16x16x32_bf16(aC, hB, zero4, 0,0,0);
        #pragma unroll
        for(int j=0;j<4;j++){
          gbf[w][0][lg*4+j][t2*16+col] = gE4[j];
          gbf[w][1][lg*4+j][t2*16+col] = gC4[j];
        }
      }
      float s8[8], m8[8];
      unp8(su, s8); unp8(mu, m8);
      float ns[8], nmv[8];
      #pragma unroll
      for(int j=0;j<8;j++){
        ns[j]  = PE*s8[j] - gbf[w][0][rr][c0+j];
        nmv[j] = PB*m8[j] + Q*s8[j] - gbf[w][1][rr][c0+j];
      }
      *(uint4*)(bsw2 + gaddr) = pck8(ns);
      *(uint4*)(bmw2 + gaddr) = pck8(nmv);
      su = svn; mu = mvn;
    }
  }
  if(c<16){
    // wait for k1's h, then o = M2new @ h_c  (A-frags re-read from own-XCD-hot bmw2)
    if(tid==0){
      while(atomicAdd(&tkA[c*B_+b], 0) < 64) __builtin_amdgcn_s_sleep(8);
    }
    __syncthreads();
    __threadfence();
    f4v oacc0 = {0.f,0.f,0.f,0.f}, oacc1 = {0.f,0.f,0.f,0.f};
    const unsigned short* mrowb = bmw2 + ((size_t)(b*D_ + d0 + col))*1024;
    #pragma unroll
    for(int sl=0; sl<8; sl++){
      int ibase = w*256 + sl*32;
      s8v mA = __builtin_bit_cast(s8v, *(const uint4*)(mrowb + ibase + lg*8));
      const unsigned short* hb2 = htic + ((size_t)(b*C_+col))*I_ + ibase + lg*8;
      s8v hB0 = __builtin_bit_cast(s8v, *(const uint4*)hb2);
      s8v hB1 = __builtin_bit_cast(s8v, *(const uint4*)(hb2 + (size_t)16*I_));
      oacc0 = __builtin_amdgcn_mfma_f32_16x16x32_bf16(mA, hB0, oacc0, 0,0,0);
      oacc1 = __builtin_amdgcn_mfma_f32_16x16x32_bf16(mA, hB1, oacc1, 0,0,0);
    }
    #pragma unroll
    for(int j=0;j<4;j++){
      xred[w][lg*4+j][col]    = oacc0[j];
      xred[w][lg*4+j][16+col] = oacc1[j];
    }
    __syncthreads();
    #pragma unroll
    for(int e=0;e<2;e++){
      int idx = tid*2+e; int row = idx>>5, t = idx&31;
      float o = xred[0][row][t]+xred[1][row][t]+xred[2][row][t]+xred[3][row][t];
      ws[OFF_OB + ((size_t)(b*C_+t))*512 + d0 + row] = o;
    }
  }
}

// ---------------- FUSED34: k3 (blocks 0..31) + k4 (all 64 blocks) ----------------
__global__ void __launch_bounds__(256,2) fused34(float* __restrict__ ws, int c){
  unsigned short* bmw2 = (unsigned short*)(ws + OFF_BST) + (size_t)3*STSZ;
  const unsigned short* dob = (const unsigned short*)(ws + OFF_DOB);
  int bx = blockIdx.x, b = blockIdx.y, tid = threadIdx.x;
  int i0 = bx*16;
  int* tkB = (int*)(ws + OFF_TK2) + 64;
  __shared__ unsigned short m2u[16][520];
  __shared__ __align__(16) float dred[4][16][32];
  __shared__ float red[32], coefl[32], bsufl[32];
  __shared__ float smr[8];
  __shared__ int lastf;
  if(bx<32){
    // ---- k3 for token t=bx ----
    int t = bx;
    int tok = b*S_ + c*32 + t;
    const float* orow = ws + OFF_OB + ((size_t)(b*32+t))*512;
    const float* krow = ws + OFF_K + (size_t)tok*512;
    const float* vrow = ws + OFF_V + (size_t)tok*512;
    const float* lrow = ws + OFF_MLN + (size_t)b*512;
    float th = ws[OFF_TH + tok];
    float o1=orow[tid], o2=orow[tid+256];
    float mu = blockReduceSum(o1*o1+o2*o2, smr)*(1.f/512.f);
    float n = rsqrtf(mu + 1e-6f);
    float l1=lrow[tid], l2=lrow[tid+256];
    float k1=krow[tid], k2=krow[tid+256];
    float v1=vrow[tid], v2=vrow[tid+256];
    float c2 = 2.f*th*(1.f/512.f);
    float u1 = c2*(k1 + o1*n*l1 - v1);
    float u2 = c2*(k2 + o2*n*l2 - v2);
    float s1 = blockReduceSum(u1*l1*o1 + u2*l2*o2, smr);
    float dln1 = u1*o1*n, dln2v = u2*o2*n;
    float fr = n*n*n*s1*(1.f/512.f);
    float do1 = n*l1*u1 - fr*o1;
    float do2 = n*l2*u2 - fr*o2;
    float don2 = blockReduceSum(do1*do1+do2*do2, smr);
    float dl2s = blockReduceSum(dln1*dln1+dln2v*dln2v, smr);
    float* dorow = ws + OFF_DO + ((size_t)(b*32+t))*512;
    float* dlrow = ws + OFF_DLN + ((size_t)(b*32+t))*512;
    dorow[tid]=do1; dorow[tid+256]=do2;
    dlrow[tid]=dln1; dlrow[tid+256]=dln2v;
    unsigned short* dobw = (unsigned short*)(ws + OFF_DOB);
    unsigned short* dotw = (unsigned short*)(ws + OFF_DOT);
    dobw[((size_t)(b*C_+t))*512 + tid]       = f2bfu(do1);
    dobw[((size_t)(b*C_+t))*512 + tid + 256] = f2bfu(do2);
    dotw[((size_t)(b*D_ + tid))*32 + t]       = f2bfu(do1);
    dotw[((size_t)(b*D_ + tid + 256))*32 + t] = f2bfu(do2);
    if(tid==0){
      float* slab = ws + OFF_SLAB + ((size_t)c*B_+b)*SLABSTR;
      slab[64+t]=don2; slab[96+t]=dl2s;
    }
    __threadfence();
    __syncthreads();
    if(tid==0) atomicAdd(&tkB[c*B_+b], 1);
  }
  // ---- stage M2^T tile (independent of k3; overlaps the wait) ----
  #pragma unroll
  for(int q=0;q<4;q++){
    int idx = tid + q*256; int d = idx>>1, half = idx&1;
    uint4 v = *(const uint4*)(bmw2 + ((size_t)(b*D_+d))*1024 + i0 + half*8);
    unsigned short tmp[8]; *(uint4*)tmp = v;
    #pragma unroll
    for(int jj=0;jj<8;jj++) m2u[half*8+jj][d] = tmp[jj];
  }
  if(tid<32) red[tid]=0.f;
  __syncthreads();
  if(tid==0){
    while(atomicAdd(&tkB[c*B_+b], 0) < 32) __builtin_amdgcn_s_sleep(8);
  }
  __syncthreads();
  __threadfence();
  int w = tid>>6, lane = tid&63;
  int col = lane&15, lg = lane>>4;
  f4v acc0 = {0.f,0.f,0.f,0.f}, acc1 = {0.f,0.f,0.f,0.f};
  #pragma unroll
  for(int ks=0;ks<4;ks++){
    int k0 = w*128 + ks*32;
    s8v mA = __builtin_bit_cast(s8v, *(const uint4*)&m2u[col][k0 + lg*8]);
    const unsigned short* dp = dob + ((size_t)(b*C_+col))*512 + k0 + lg*8;
    s8v dB0 = __builtin_bit_cast(s8v, *(const uint4*)dp);
    s8v dB1 = __builtin_bit_cast(s8v, *(const uint4*)(dp + (size_t)16*512));
    acc0 = __builtin_amdgcn_mfma_f32_16x16x32_bf16(mA, dB0, acc0, 0,0,0);
    acc1 = __builtin_amdgcn_mfma_f32_16x16x32_bf16(mA, dB1, acc1, 0,0,0);
  }
  #pragma unroll
  for(int j=0;j<4;j++){
    dred[w][lg*4+j][col]    = acc0[j];
    dred[w][lg*4+j][16+col] = acc1[j];
  }
  __syncthreads();
  #pragma unroll
  for(int e=0;e<2;e++){
    int idx = tid*2+e; int row = idx>>5, t = idx&31;
    float dh = dred[0][row][t]+dred[1][row][t]+dred[2][row][t]+dred[3][row][t];
    size_t zb = ((size_t)(b*I_ + i0 + row))*32 + t;
    float z = ws[OFF_Z1+zb];
    float s = 1.f/(1.f+expf(-z));
    float dp_ = dh * s*(1.f + z*(1.f-s));
    ws[OFF_DHP+zb] = dp_;
    atomicAdd(&red[t], dp_*dp_);
  }
  __syncthreads();
  float* slab = ws + OFF_SLAB + ((size_t)c*B_+b)*SLABSTR;
  if(tid<32) atomicAdd(&slab[32+tid], red[tid]);
  __threadfence();
  __syncthreads();
  if(tid==0){
    int* tick = (int*)(ws+OFF_TICK);
    lastf = (atomicAdd(&tick[c*B_+b],1) == 63) ? 1 : 0;
  }
  __syncthreads();
  if(!lastf) return;
  if(tid<32){
    float sqd = atomicAdd(&slab[32+tid], 0.f);
    float hn  = atomicAdd(&slab[0+tid], 0.f);
    float don2 = slab[64+tid], dl2 = slab[96+tid];
    float kn2 = ws[OFF_KN2 + b*S_ + c*32 + tid];
    float sq = sqd*kn2 + don2*hn + dl2;
    coefl[tid] = fminf(1.f/(sqrtf(sq)+1e-6f), 1.f);
  }
  __syncthreads();
  if(tid==0){
    const float* eta = ws + OFF_ET + b*S_ + c*32;
    const float* alp = ws + OFF_AL + b*S_ + c*32;
    float Esuf=1.f, Bsuf=1.f, cu=1.f;
    for(int u=31;u>=0;u--){
      if(u<31){
        float e1 = eta[u+1], b1 = 1.f-alp[u+1];
        Esuf *= e1; Bsuf *= b1;
        cu = Bsuf + e1*cu;
      }
      bsufl[u]=Bsuf;
      slab[128+u] = Esuf*coefl[u];
      slab[160+u] = cu*coefl[u];
    }
    float PE = Esuf*eta[0];
    float PB = Bsuf*(1.f-alp[0]);
    float Q=0.f, Epre=1.f;
    for(int t2=0;t2<32;t2++){ Epre *= eta[t2]; Q += bsufl[t2]*Epre; }
    slab[192]=PE; slab[193]=PB; slab[194]=Q;
  }
}

// ---------------- R1 (MFMA): hq = silu(q @ M1^T), bf16 out ----------------
__global__ void __launch_bounds__(256) r1_gemm(float* __restrict__ ws){
  const unsigned short* qbf = (const unsigned short*)(ws + OFF_ORET + KBUF/2);
  const unsigned short* bmw1 = (const unsigned short*)(ws + OFF_BST) + STSZ;
  unsigned short* hqb = (unsigned short*)(ws + OFF_K);
  int b = blockIdx.z;
  int s0 = blockIdx.x*64, i0 = blockIdx.y*64;
  int w = threadIdx.x>>6, lane = threadIdx.x&63;
  int col = lane&15, lg = lane>>4;
  const unsigned short* qb = qbf + (size_t)b*S_*D_;
  const unsigned short* w1b = bmw1 + (size_t)b*I_*D_;
  f4v acc[4] = {{0,0,0,0},{0,0,0,0},{0,0,0,0},{0,0,0,0}};
  for(int k0=0;k0<512;k0+=32){
    s8v bB = __builtin_bit_cast(s8v, *(const uint4*)(w1b + (size_t)(i0 + w*16 + col)*512 + k0 + lg*8));
    #pragma unroll
    for(int rg=0;rg<4;rg++){
      s8v aA = __builtin_bit_cast(s8v, *(const uint4*)(qb + (size_t)(s0 + rg*16 + col)*512 + k0 + lg*8));
      acc[rg] = __builtin_amdgcn_mfma_f32_16x16x32_bf16(aA, bB, acc[rg], 0,0,0);
    }
  }
  unsigned short* hb = hqb + (size_t)b*S_*I_;
  #pragma unroll
  for(int rg=0;rg<4;rg++)
    #pragma unroll
    for(int j=0;j<4;j++){
      float z = acc[rg][j];
      hb[(size_t)(s0 + rg*16 + lg*4 + j)*1024 + i0 + w*16 + col] = f2bfu(z/(1.f+expf(-z)));
    }
}

// ---------------- R2 (MFMA): oret = hq @ M2^T ----------------
__global__ void __launch_bounds__(256) r2_gemm(float* __restrict__ ws){
  const unsigned short* hqb = (const unsigned short*)(ws + OFF_K);
  const unsigned short* bmw2 = (const unsigned short*)(ws + OFF_BST) + (size_t)3*STSZ;
  int b=blockIdx.z;
  int s0=blockIdx.x*64, d0=blockIdx.y*64;
  int w = threadIdx.x>>6, lane = threadIdx.x&63;
  int col = lane&15, lg = lane>>4;
  const unsigned short* hb = hqb + (size_t)b*S_*I_;
  const unsigned short* w2b = bmw2 + (size_t)b*D_*I_;
  f4v acc[4] = {{0,0,0,0},{0,0,0,0},{0,0,0,0},{0,0,0,0}};
  for(int k0=0;k0<1024;k0+=32){
    s8v bB = __builtin_bit_cast(s8v, *(const uint4*)(w2b + (size_t)(d0 + w*16 + col)*1024 + k0 + lg*8));
    #pragma unroll
    for(int rg=0;rg<4;rg++){
      s8v aA = __builtin_bit_cast(s8v, *(const uint4*)(hb + (size_t)(s0 + rg*16 + col)*1024 + k0 + lg*8));
      acc[rg] = __builtin_amdgcn_mfma_f32_16x16x32_bf16(aA, bB, acc[rg], 0,0,0);
    }
  }
  float* od = ws + OFF_ORET + (size_t)b*S_*D_;
  #pragma unroll
  for(int rg=0;rg<4;rg++)
    #pragma unroll
    for(int j=0;j<4;j++)
      od[(size_t)(s0 + rg*16 + lg*4 + j)*512 + d0 + w*16 + col] = acc[rg][j];
}

// ---------------- R3: out = q + rms(oret, Mln) ----------------
__global__ void __launch_bounds__(256) r3_out(float* __restrict__ ws, void* __restrict__ out){
  int f = ((const int*)(ws+OFF_FLAG))[0];
  int tok=blockIdx.x, tid=threadIdx.x;
  int b = tok >> 9;
  __shared__ float sm[8];
  const float* orow = ws + OFF_ORET + (size_t)tok*512;
  const float* qrow = ws + OFF_Q + (size_t)tok*512;
  const float* lrow = ws + OFF_MLN + (size_t)b*512;
  float o1=orow[tid], o2=orow[tid+256];
  float mu = blockReduceSum(o1*o1+o2*o2, sm)*(1.f/512.f);
  float n = rsqrtf(mu+1e-6f);
  float r1v = qrow[tid]     + o1*n*lrow[tid];
  float r2v = qrow[tid+256] + o2*n*lrow[tid+256];
  if(f){
    ((float*)out)[(size_t)tok*512+tid]     = r1v;
    ((float*)out)[(size_t)tok*512+tid+256] = r2v;
  } else {
    ((__hip_bfloat16*)out)[(size_t)tok*512+tid]     = __float2bfloat16(r1v);
    ((__hip_bfloat16*)out)[(size_t)tok*512+tid+256] = __float2bfloat16(r2v);
  }
}

extern "C" void kernel_launch(void* const* d_in, const int* in_sizes, int n_in,
                              void* d_out, int out_size, void* d_ws, size_t ws_size,
                              hipStream_t stream) {
  const void* x  = d_in[0];
  const void* wq = d_in[1];
  const void* wk = d_in[2];
  const void* wv = d_in[3];
  const void* qn = d_in[4];
  const void* kn = d_in[5];
  const void* aw = d_in[6];
  const void* tw = d_in[7];
  const void* ew = d_in[8];
  const void* w1 = d_in[9];
  const void* w2 = d_in[10];
  const void* ln = d_in[11];
  float* ws = (float*)d_ws;

  d0_detect<<<1,64,0,stream>>>(x, ws);
  p0_init<<<2048,256,0,stream>>>(ws, w1, w2, ln);
  cvt_in<<<2048,256,0,stream>>>(x, wk, wv, wq, ws);
  p1a<<<dim3(32,8,3),256,0,stream>>>(ws);
  p1b<<<2048,256,0,stream>>>(x, kn, qn, aw, tw, ew, ws);
  tr_k<<<dim3(8,8,4),256,0,stream>>>(ws);
  for(int c=0;c<=16;c++){
    fused12<<<dim3(97,B_),256,0,stream>>>(ws, c);
    if(c<16) fused34<<<dim3(64,B_),256,0,stream>>>(ws, c);
  }
  r1_gemm<<<dim3(8,16,4),256,0,stream>>>(ws);
  r2_gemm<<<dim3(8,8,4),256,0,stream>>>(ws);
  r3_out<<<2048,256,0,stream>>>(ws, d_out);
}

// Round 6
// 1404.388 us; speedup vs baseline: 1.6647x; 1.6647x over previous
//
#include <hip/hip_runtime.h>
#include <hip/hip_bf16.h>

#define B_ 4
#define S_ 512
#define D_ 512
#define I_ 1024
#define C_ 32
#define NC_ 16

// ---- ws layout (float offsets) ----
#define KBUF (B_*S_*D_)
#define STSZ (B_*I_*D_)
#define HSZ  (B_*I_*C_)
#define DOSZ (B_*C_*D_)
#define OFF_K    0
#define OFF_V    (OFF_K + KBUF)
#define OFF_Q    (OFF_V + KBUF)
#define OFF_TH   (OFF_Q + KBUF)
#define OFF_AL   (OFF_TH + B_*S_)
#define OFF_ET   (OFF_AL + B_*S_)
#define OFF_KN2  (OFF_ET + B_*S_)
#define OFF_SLN  (OFF_KN2 + B_*S_)
#define OFF_MLN  (OFF_SLN + B_*D_)
#define OFF_H2   (OFF_MLN + B_*D_)
#define OFF_Z1   (OFF_H2 + 2*HSZ)
#define OFF_DHP  (OFF_Z1 + HSZ)
#define OFF_DO   (OFF_DHP + HSZ)
#define OFF_DLN  (OFF_DO + DOSZ)
#define OFF_OB   (OFF_DLN + DOSZ)
#define OFF_SLAB (OFF_OB + DOSZ)
#define SLABSTR  256
#define OFF_TICK (OFF_SLAB + NC_*B_*SLABSTR)
#define OFF_TK2  (OFF_TICK + 64)             // (reserved)
#define OFF_FLAG (OFF_TK2 + 128)
#define OFF_ORET (OFF_FLAG + 16)
#define OFF_BST  (OFF_ORET + KBUF)     // bf16 states start here (ushort*)
// bf16 state arrays (ushort element offsets within bst):
//   BSW1 = 0, BMW1 = STSZ, BSW2 = 2*STSZ, BMW2 = 3*STSZ
#define OFF_KBFf (OFF_BST + 2*STSZ)          // kbf[b][s][d] bf16 (KBUF ushorts)
#define OFF_KBTf (OFF_KBFf + KBUF/2)         // kbt[b][d][s] bf16 (KBUF ushorts)
#define OFF_HIT  (OFF_KBTf + KBUF/2)         // h [buf][b][i][t] bf16
#define OFF_HTI  (OFF_HIT + HSZ)             // h [buf][b][t][i] bf16
#define OFF_DOB  (OFF_HTI + HSZ)             // (unused, layout spacing)
#define OFF_DOT  (OFF_DOB + DOSZ/2)          // do [b][d][t] bf16
// aliases (temporally disjoint):
//   xbf (bf16 x, pre-loop)        -> OFF_ORET lower half
//   qbf (bf16 q, from p1b)        -> OFF_ORET upper half (until r2 writes oret)
//   wbf (bf16 wk/wv/wq, pre-loop) -> OFF_KBFf region (tr_k overwrites after p1a)
//   hqb (bf16 hq, post-loop)      -> OFF_K region (k f32 dead after loop)

typedef __attribute__((ext_vector_type(8))) short s8v;    // 8 bf16 in 4 VGPR
typedef __attribute__((ext_vector_type(4))) float f4v;    // mfma C/D

__device__ __forceinline__ float bf2f(__hip_bfloat16 v){ return __bfloat162float(v); }
__device__ __forceinline__ float bfu2f(unsigned short u){ return __uint_as_float(((unsigned)u)<<16); }
__device__ __forceinline__ unsigned short f2bfu(float f){
  unsigned x = __float_as_uint(f);
  return (unsigned short)((x + 0x7FFFu + ((x>>16)&1u)) >> 16);
}
__device__ __forceinline__ float4 u42f4(ushort4 u){
  float4 r; r.x=bfu2f(u.x); r.y=bfu2f(u.y); r.z=bfu2f(u.z); r.w=bfu2f(u.w); return r;
}
__device__ __forceinline__ ushort4 f42u4(float4 v){
  ushort4 r; r.x=f2bfu(v.x); r.y=f2bfu(v.y); r.z=f2bfu(v.z); r.w=f2bfu(v.w); return r;
}
__device__ __forceinline__ float ldin(const void* p, size_t i, int f){
  return f ? ((const float*)p)[i] : bf2f(((const __hip_bfloat16*)p)[i]);
}
__device__ __forceinline__ float4 ld4g(const void* p, size_t i, int f){
  if(f) return ((const float4*)p)[i>>2];
  return u42f4(((const ushort4*)p)[i>>2]);
}
__device__ __forceinline__ void unp8(uint4 u, float* f){
  f[0]=bfu2f((unsigned short)(u.x&0xffffu)); f[1]=bfu2f((unsigned short)(u.x>>16));
  f[2]=bfu2f((unsigned short)(u.y&0xffffu)); f[3]=bfu2f((unsigned short)(u.y>>16));
  f[4]=bfu2f((unsigned short)(u.z&0xffffu)); f[5]=bfu2f((unsigned short)(u.z>>16));
  f[6]=bfu2f((unsigned short)(u.w&0xffffu)); f[7]=bfu2f((unsigned short)(u.w>>16));
}
__device__ __forceinline__ uint4 pck8(const float* f){
  uint4 u;
  u.x = (unsigned)f2bfu(f[0]) | ((unsigned)f2bfu(f[1])<<16);
  u.y = (unsigned)f2bfu(f[2]) | ((unsigned)f2bfu(f[3])<<16);
  u.z = (unsigned)f2bfu(f[4]) | ((unsigned)f2bfu(f[5])<<16);
  u.w = (unsigned)f2bfu(f[6]) | ((unsigned)f2bfu(f[7])<<16);
  return u;
}

__device__ __forceinline__ float blockReduceSum(float v, float* sm){
  #pragma unroll
  for(int o=32;o>0;o>>=1) v += __shfl_down(v,o,64);
  int wid = threadIdx.x>>6, lane = threadIdx.x&63;
  __syncthreads();
  if(lane==0) sm[wid]=v;
  __syncthreads();
  return sm[0]+sm[1]+sm[2]+sm[3];
}

__device__ __forceinline__ float wred(float v){
  #pragma unroll
  for(int o=32;o>0;o>>=1) v += __shfl_xor(v,o,64);
  return v;
}

// ---------------- D0: runtime input-dtype detection ----------------
__global__ void d0_detect(const void* __restrict__ x, float* __restrict__ ws){
  __shared__ int cnt;
  if(threadIdx.x==0) cnt=0;
  __syncthreads();
  unsigned w = ((const unsigned*)x)[(size_t)threadIdx.x*931 + 17];
  int e = (w>>7)&0xFF;
  if(e>=110 && e<=140) atomicAdd(&cnt,1);
  __syncthreads();
  if(threadIdx.x==0) ((int*)(ws+OFF_FLAG))[0] = (cnt<32) ? 1 : 0;  // 1 => f32 inputs
}

// ---------------- P0: init states / slabs / ticks + cvt x,wk/wv/wq -> bf16 ----------------
__global__ void p0_init(float* __restrict__ ws, const void* __restrict__ w1,
                        const void* __restrict__ w2, const void* __restrict__ ln,
                        const void* __restrict__ x, const void* __restrict__ wk,
                        const void* __restrict__ wv, const void* __restrict__ wq){
  int f = ((const int*)(ws+OFF_FLAG))[0];
  unsigned short* bst = (unsigned short*)(ws + OFF_BST);
  size_t id = (size_t)blockIdx.x*blockDim.x + threadIdx.x;
  size_t stride = (size_t)gridDim.x*blockDim.x;
  ushort4 z4 = {0,0,0,0};
  for(size_t t4=id; t4<(size_t)(STSZ/4); t4+=stride){
    size_t e4 = t4 % (size_t)(I_*D_/4);
    *(ushort4*)(bst + (size_t)STSZ + t4*4)   = f42u4(ld4g(w1, e4*4, f));  // BMW1
    *(ushort4*)(bst + (size_t)3*STSZ + t4*4) = f42u4(ld4g(w2, e4*4, f));  // BMW2
    *(ushort4*)(bst + t4*4) = z4;                                          // BSW1
    *(ushort4*)(bst + (size_t)2*STSZ + t4*4) = z4;                         // BSW2
  }
  unsigned short* xbf = (unsigned short*)(ws + OFF_ORET);
  unsigned short* wbf = (unsigned short*)(ws + OFF_KBFf);
  for(size_t t4=id; t4<(size_t)(KBUF/4); t4+=stride)
    *(ushort4*)(xbf + t4*4) = f42u4(ld4g(x, t4*4, f));
  for(size_t t4=id; t4<(size_t)(3*D_*D_/4); t4+=stride){
    int pid = (int)(t4 / (D_*D_/4));
    size_t e4 = t4 % (size_t)(D_*D_/4);
    const void* W = (pid==0)?wk:((pid==1)?wv:wq);
    *(ushort4*)(wbf + t4*4) = f42u4(ld4g(W, e4*4, f));
  }
  for(size_t t=id; t<(size_t)(B_*D_); t+=stride){
    ws[OFF_MLN+t] = ldin(ln,t % D_,f);
    ws[OFF_SLN+t] = 0.f;
  }
  for(size_t t=id; t<(size_t)(NC_*B_*SLABSTR); t+=stride) ws[OFF_SLAB+t]=0.f;
  int* tick = (int*)(ws + OFF_TICK);
  for(size_t t=id; t<192; t+=stride) tick[t]=0;
}

// ---------------- P1a (MFMA): k,v,q = silu(x@W^T) ----------------
// grid dim3(32,8,3): blockIdx.x spans ALL B*S = 2048 rows / 64
__global__ void __launch_bounds__(256) p1a(float* __restrict__ ws){
  const unsigned short* xbf = (const unsigned short*)(ws + OFF_ORET);
  const unsigned short* wbf = (const unsigned short*)(ws + OFF_KBFf);
  int pid = blockIdx.z;
  float* outp = ws + ((pid==0)?OFF_K:((pid==1)?OFF_V:OFF_Q));
  const unsigned short* W = wbf + (size_t)pid*D_*D_;
  int r0 = blockIdx.x*64, j0 = blockIdx.y*64;
  int w = threadIdx.x>>6, lane = threadIdx.x&63;
  int col = lane&15, lg = lane>>4;
  f4v acc[4] = {{0,0,0,0},{0,0,0,0},{0,0,0,0},{0,0,0,0}};
  for(int k0=0;k0<512;k0+=32){
    s8v bB = __builtin_bit_cast(s8v, *(const uint4*)(W + (size_t)(j0 + w*16 + col)*512 + k0 + lg*8));
    #pragma unroll
    for(int rg=0;rg<4;rg++){
      s8v aA = __builtin_bit_cast(s8v, *(const uint4*)(xbf + (size_t)(r0 + rg*16 + col)*512 + k0 + lg*8));
      acc[rg] = __builtin_amdgcn_mfma_f32_16x16x32_bf16(aA, bB, acc[rg], 0,0,0);
    }
  }
  #pragma unroll
  for(int rg=0;rg<4;rg++)
    #pragma unroll
    for(int j=0;j<4;j++){
      float z = acc[rg][j];
      outp[(size_t)(r0 + rg*16 + lg*4 + j)*512 + j0 + w*16 + col] = z/(1.f+expf(-z));
    }
}

// ---------------- P1b: rms(k),rms(q)(+bf16 q), |k|^2, gates ----------------
__global__ void __launch_bounds__(256) p1b(const void* __restrict__ x,
                    const void* __restrict__ kn,
                    const void* __restrict__ qn,
                    const void* __restrict__ aw,
                    const void* __restrict__ tw,
                    const void* __restrict__ ew,
                    float* __restrict__ ws){
  int f = ((const int*)(ws+OFF_FLAG))[0];
  int tok = blockIdx.x; int tid = threadIdx.x;
  __shared__ float sm[8];
  float* krow = ws + OFF_K + (size_t)tok*512;
  float* qrow = ws + OFF_Q + (size_t)tok*512;
  float a = krow[tid], b = krow[tid+256];
  float ss = blockReduceSum(a*a+b*b, sm);
  float n = rsqrtf(ss*(1.f/512.f) + 1e-6f);
  float k1v = a*n*ldin(kn,tid,f);
  float k2v = b*n*ldin(kn,tid+256,f);
  krow[tid]=k1v; krow[tid+256]=k2v;
  float kn2 = blockReduceSum(k1v*k1v+k2v*k2v, sm);
  if(tid==0) ws[OFF_KN2+tok]=kn2;
  a = qrow[tid]; b = qrow[tid+256];
  ss = blockReduceSum(a*a+b*b, sm);
  n = rsqrtf(ss*(1.f/512.f)+1e-6f);
  float q1 = a*n*ldin(qn,tid,f);
  float q2 = b*n*ldin(qn,tid+256,f);
  qrow[tid]=q1; qrow[tid+256]=q2;
  unsigned short* qbf = (unsigned short*)(ws + OFF_ORET + KBUF/2);
  qbf[(size_t)tok*512+tid]     = f2bfu(q1);
  qbf[(size_t)tok*512+tid+256] = f2bfu(q2);
  float x1=ldin(x,(size_t)tok*512+tid,f), x2=ldin(x,(size_t)tok*512+tid+256,f);
  float td = blockReduceSum(x1*ldin(tw,tid,f) + x2*ldin(tw,tid+256,f), sm);
  float ad = blockReduceSum(x1*ldin(aw,tid,f) + x2*ldin(aw,tid+256,f), sm);
  float ed = blockReduceSum(x1*ldin(ew,tid,f) + x2*ldin(ew,tid+256,f), sm);
  if(tid==0){
    ws[OFF_TH+tok] = 0.01f/(1.f+expf(-td));
    ws[OFF_AL+tok] = 1.f/(1.f+expf(-ad));
    ws[OFF_ET+tok] = 1.f/(1.f+expf(-ed));
  }
}

// ---------------- TRK: snapshot normalized K as bf16, both orientations ----------------
__global__ void __launch_bounds__(256) tr_k(float* __restrict__ ws){
  unsigned short* kbf = (unsigned short*)(ws + OFF_KBFf);
  unsigned short* kbt = (unsigned short*)(ws + OFF_KBTf);
  int b = blockIdx.z, st = blockIdx.y, dt = blockIdx.x;
  int s0 = st*64, d0 = dt*64;
  __shared__ unsigned short t[64][72];
  int tid = threadIdx.x;
  #pragma unroll
  for(int q=0;q<4;q++){
    int idx = tid + q*256; int r = idx>>4, cq = idx&15;
    float4 v = *(const float4*)(ws + OFF_K + ((size_t)(b*512 + s0 + r))*512 + d0 + cq*4);
    ushort4 u; u.x=f2bfu(v.x); u.y=f2bfu(v.y); u.z=f2bfu(v.z); u.w=f2bfu(v.w);
    *(ushort4*)&t[r][cq*4] = u;
    *(ushort4*)(kbf + ((size_t)(b*512 + s0 + r))*512 + d0 + cq*4) = u;
  }
  __syncthreads();
  #pragma unroll
  for(int q=0;q<4;q++){
    int idx = tid + q*256; int d = idx>>4, sq = idx&15;
    ushort4 u; u.x=t[sq*4+0][d]; u.y=t[sq*4+1][d]; u.z=t[sq*4+2][d]; u.w=t[sq*4+3][d];
    *(ushort4*)(kbt + ((size_t)(b*512 + d0 + d))*512 + s0 + sq*4) = u;
  }
}

// ---------------- K1 (MFMA): update W1(+ln) w/ chunk c-1 grads; z,h for chunk c ----------------
__global__ void __launch_bounds__(256) k1_w1(float* __restrict__ ws, int c){
  unsigned short* bsw1 = (unsigned short*)(ws + OFF_BST);
  unsigned short* bmw1 = bsw1 + STSZ;
  const unsigned short* kbf = (const unsigned short*)(ws + OFF_KBFf);
  const unsigned short* kbt = (const unsigned short*)(ws + OFF_KBTf);
  int b = blockIdx.y, bx = blockIdx.x, tid = threadIdx.x;
  __shared__ float sE[32], sC[32], scal[3];
  if(c>0){
    const float* slab = ws + OFF_SLAB + ((long)(c-1)*B_ + b)*SLABSTR;
    if(tid<32){ sE[tid]=slab[128+tid]; sC[tid]=slab[160+tid]; }
    if(tid>=32 && tid<35) scal[tid-32]=slab[192+(tid-32)];
  }
  __syncthreads();
  float PE = c>0? scal[0]:1.f, PB = c>0? scal[1]:1.f, Q = c>0? scal[2]:0.f;
  if(bx==64){
    if(c>0){
      for(int d=tid; d<512; d+=256){
        float gE=0,gC=0;
        for(int u=0;u<32;u++){
          float dl = ws[OFF_DLN + ((size_t)(b*32+u))*512 + d];
          gE += sE[u]*dl; gC += sC[u]*dl;
        }
        size_t ix = OFF_SLN + (size_t)b*512 + d;
        float sv=ws[ix], mv=ws[ix + (OFF_MLN-OFF_SLN)];
        ws[ix] = PE*sv - gE;
        ws[ix + (OFF_MLN-OFF_SLN)] = PB*mv + Q*sv - gC;
      }
    }
    return;
  }
  __shared__ __align__(16) float gbf[4][2][16][36];
  __shared__ __align__(16) unsigned short ztile[4][16][40];
  __shared__ __align__(16) float zred[4][16][32];
  __shared__ float hredL[32];
  int w = tid>>6, lane = tid&63;
  int i0 = bx*16;
  int col = lane&15, lg = lane>>4;
  int rr = lane>>2, c0 = (lane&3)*8;
  s8v aE = {}, aC = {};
  if(c>0){
    const float* dp = ws + OFF_DHP + ((size_t)(b*I_ + i0 + col))*32 + lg*8;
    float4 dv0 = *(const float4*)dp;
    float4 dv1 = *(const float4*)(dp+4);
    float dv[8] = {dv0.x,dv0.y,dv0.z,dv0.w,dv1.x,dv1.y,dv1.z,dv1.w};
    #pragma unroll
    for(int j=0;j<8;j++){
      aE[j] = (short)f2bfu(sE[lg*8+j]*dv[j]);
      aC[j] = (short)f2bfu(sC[lg*8+j]*dv[j]);
    }
  }
  f4v zacc0 = {0.f,0.f,0.f,0.f}, zacc1 = {0.f,0.f,0.f,0.f};
  const int d0w = w*128;
  const size_t srowbase = ((size_t)(b*I_ + i0))*512;
  const size_t kprow = (size_t)(c-1)*32;
  for(int sl=0; sl<4; sl++){
    int dbase = d0w + sl*32;
    size_t gaddr = srowbase + (size_t)rr*512 + dbase + c0;
    if(c>0){
      #pragma unroll
      for(int t2=0;t2<2;t2++){
        int dt = dbase + t2*16;
        const unsigned short* kp = kbt + ((size_t)(b*512 + dt + col))*512 + kprow + lg*8;
        s8v kB = __builtin_bit_cast(s8v, *(const uint4*)kp);
        f4v zero4 = {0.f,0.f,0.f,0.f};
        f4v gE4 = __builtin_amdgcn_mfma_f32_16x16x32_bf16(aE, kB, zero4, 0,0,0);
        f4v gC4 = __builtin_amdgcn_mfma_f32_16x16x32_bf16(aC, kB, zero4, 0,0,0);
        #pragma unroll
        for(int j=0;j<4;j++){
          gbf[w][0][lg*4+j][t2*16+col] = gE4[j];
          gbf[w][1][lg*4+j][t2*16+col] = gC4[j];
        }
      }
      uint4 su = *(uint4*)(bsw1 + gaddr);
      uint4 mu = *(uint4*)(bmw1 + gaddr);
      float s8[8], m8[8];
      unp8(su, s8); unp8(mu, m8);
      float ns[8], nmv[8];
      #pragma unroll
      for(int j=0;j<8;j++){
        float ge = gbf[w][0][rr][c0+j];
        float gc = gbf[w][1][rr][c0+j];
        ns[j]  = PE*s8[j] - ge;
        nmv[j] = PB*m8[j] + Q*s8[j] - gc;
      }
      *(uint4*)(bsw1 + gaddr) = pck8(ns);
      uint4 nmu = pck8(nmv);
      *(uint4*)(bmw1 + gaddr) = nmu;
      *(uint4*)&ztile[w][rr][c0] = nmu;
    } else {
      uint4 mu = *(uint4*)(bmw1 + gaddr);
      *(uint4*)&ztile[w][rr][c0] = mu;
    }
    if(c<16){
      s8v mA = __builtin_bit_cast(s8v, *(const uint4*)&ztile[w][col][lg*8]);
      const unsigned short* kc0 = kbf + ((size_t)(b*512 + c*32 + col))*512 + dbase + lg*8;
      s8v kB0 = __builtin_bit_cast(s8v, *(const uint4*)kc0);
      s8v kB1 = __builtin_bit_cast(s8v, *(const uint4*)(kc0 + (size_t)16*512));
      zacc0 = __builtin_amdgcn_mfma_f32_16x16x32_bf16(mA, kB0, zacc0, 0,0,0);
      zacc1 = __builtin_amdgcn_mfma_f32_16x16x32_bf16(mA, kB1, zacc1, 0,0,0);
    }
  }
  if(c<16){
    #pragma unroll
    for(int j=0;j<4;j++){
      zred[w][lg*4+j][col]    = zacc0[j];
      zred[w][lg*4+j][16+col] = zacc1[j];
    }
    if(tid<32) hredL[tid]=0.f;
    __syncthreads();
    unsigned short* hit = (unsigned short*)(ws + OFF_HIT) + (size_t)(c&1)*HSZ;
    unsigned short* hti = (unsigned short*)(ws + OFF_HTI) + (size_t)(c&1)*HSZ;
    #pragma unroll
    for(int e=0;e<2;e++){
      int idx = tid*2+e; int row = idx>>5, t = idx&31;
      float z = zred[0][row][t]+zred[1][row][t]+zred[2][row][t]+zred[3][row][t];
      size_t zb = ((size_t)(b*I_ + i0 + row))*32 + t;
      ws[OFF_Z1+zb] = z;
      float h = z/(1.f+expf(-z));
      unsigned short hb = f2bfu(h);
      hit[zb] = hb;
      hti[((size_t)(b*C_+t))*I_ + i0 + row] = hb;
      atomicAdd(&hredL[t], h*h);
    }
    __syncthreads();
    if(tid<32) atomicAdd(ws + OFF_SLAB + ((size_t)c*B_ + b)*SLABSTR + tid, hredL[tid]);
  }
}

// ---------------- K2 (MFMA): update W2 w/ chunk c-1 grads; o = M2@h_c ----------------
__global__ void __launch_bounds__(256) k2_w2(float* __restrict__ ws, int c){
  unsigned short* bsw2 = (unsigned short*)(ws + OFF_BST) + (size_t)2*STSZ;
  unsigned short* bmw2 = bsw2 + STSZ;
  const unsigned short* hitp = (const unsigned short*)(ws + OFF_HIT) + (size_t)((c-1)&1)*HSZ;
  const unsigned short* htic = (const unsigned short*)(ws + OFF_HTI) + (size_t)(c&1)*HSZ;
  const unsigned short* dotb = (const unsigned short*)(ws + OFF_DOT);
  int b = blockIdx.y, bx = blockIdx.x, tid = threadIdx.x;
  int d0 = bx*16;
  __shared__ float sE[32], sC[32], scal[3];
  __shared__ __align__(16) float gbf[4][2][16][36];
  __shared__ __align__(16) unsigned short ztile[4][16][40];
  __shared__ __align__(16) float ored[4][16][32];
  if(c>0){
    const float* slab = ws + OFF_SLAB + ((long)(c-1)*B_+b)*SLABSTR;
    if(tid<32){ sE[tid]=slab[128+tid]; sC[tid]=slab[160+tid]; }
    if(tid>=32&&tid<35) scal[tid-32]=slab[192+tid-32];
  }
  __syncthreads();
  float PE = c>0?scal[0]:1.f, PB=c>0?scal[1]:1.f, Q=c>0?scal[2]:0.f;
  int w = tid>>6, lane = tid&63;
  int col = lane&15, lg = lane>>4;
  int rr = lane>>2, c0 = (lane&3)*8;
  s8v aE = {}, aC = {};
  if(c>0){
    const unsigned short* dp = dotb + ((size_t)(b*D_ + d0 + col))*32 + lg*8;
    float dv[8]; unp8(*(const uint4*)dp, dv);
    #pragma unroll
    for(int j=0;j<8;j++){
      aE[j] = (short)f2bfu(sE[lg*8+j]*dv[j]);
      aC[j] = (short)f2bfu(sC[lg*8+j]*dv[j]);
    }
  }
  f4v oacc0 = {0.f,0.f,0.f,0.f}, oacc1 = {0.f,0.f,0.f,0.f};
  const size_t srowbase = ((size_t)(b*D_ + d0))*1024;
  size_t ga0 = srowbase + (size_t)rr*1024 + w*256 + c0;
  uint4 su={0,0,0,0}, mu, svn=su, mvn;
  if(c>0) su = *(uint4*)(bsw2 + ga0);
  mu = *(uint4*)(bmw2 + ga0);
  for(int sl=0; sl<8; sl++){
    int ibase = w*256 + sl*32;
    size_t gaddr = srowbase + (size_t)rr*1024 + ibase + c0;
    if(sl<7){
      if(c>0) svn = *(uint4*)(bsw2 + gaddr + 32);
      mvn = *(uint4*)(bmw2 + gaddr + 32);
    }
    if(c>0){
      #pragma unroll
      for(int t2=0;t2<2;t2++){
        const unsigned short* hp = hitp + ((size_t)(b*I_ + ibase + t2*16 + col))*32 + lg*8;
        s8v hB = __builtin_bit_cast(s8v, *(const uint4*)hp);
        f4v zero4 = {0.f,0.f,0.f,0.f};
        f4v gE4 = __builtin_amdgcn_mfma_f32_16x16x32_bf16(aE, hB, zero4, 0,0,0);
        f4v gC4 = __builtin_amdgcn_mfma_f32_16x16x32_bf16(aC, hB, zero4, 0,0,0);
        #pragma unroll
        for(int j=0;j<4;j++){
          gbf[w][0][lg*4+j][t2*16+col] = gE4[j];
          gbf[w][1][lg*4+j][t2*16+col] = gC4[j];
        }
      }
      float s8[8], m8[8];
      unp8(su, s8); unp8(mu, m8);
      float ns[8], nmv[8];
      #pragma unroll
      for(int j=0;j<8;j++){
        ns[j]  = PE*s8[j] - gbf[w][0][rr][c0+j];
        nmv[j] = PB*m8[j] + Q*s8[j] - gbf[w][1][rr][c0+j];
      }
      *(uint4*)(bsw2 + gaddr) = pck8(ns);
      uint4 nmu = pck8(nmv);
      *(uint4*)(bmw2 + gaddr) = nmu;
      *(uint4*)&ztile[w][rr][c0] = nmu;
    } else {
      *(uint4*)&ztile[w][rr][c0] = mu;
    }
    if(c<16){
      s8v mA = __builtin_bit_cast(s8v, *(const uint4*)&ztile[w][col][lg*8]);
      const unsigned short* hb = htic + ((size_t)(b*C_+col))*I_ + ibase + lg*8;
      s8v hB0 = __builtin_bit_cast(s8v, *(const uint4*)hb);
      s8v hB1 = __builtin_bit_cast(s8v, *(const uint4*)(hb + (size_t)16*I_));
      oacc0 = __builtin_amdgcn_mfma_f32_16x16x32_bf16(mA, hB0, oacc0, 0,0,0);
      oacc1 = __builtin_amdgcn_mfma_f32_16x16x32_bf16(mA, hB1, oacc1, 0,0,0);
    }
    su = svn; mu = mvn;
  }
  if(c<16){
    #pragma unroll
    for(int j=0;j<4;j++){
      ored[w][lg*4+j][col]    = oacc0[j];
      ored[w][lg*4+j][16+col] = oacc1[j];
    }
    __syncthreads();
    #pragma unroll
    for(int e=0;e<2;e++){
      int idx = tid*2+e; int row = idx>>5, t = idx&31;
      float o = ored[0][row][t]+ored[1][row][t]+ored[2][row][t]+ored[3][row][t];
      ws[OFF_OB + ((size_t)(b*C_+t))*512 + d0 + row] = o;
    }
  }
}

// ---------------- K34: k3 (redundant, wave-parallel, LDS do) + k4 GEMM ----------------
// grid dim3(64, B_); no cross-block waiting (tick/lastf tail only)
__global__ void __launch_bounds__(256) k34(float* __restrict__ ws, int c){
  unsigned short* bmw2 = (unsigned short*)(ws + OFF_BST) + (size_t)3*STSZ;
  int bx = blockIdx.x, b = blockIdx.y, tid = threadIdx.x;
  int i0 = bx*16;
  __shared__ __align__(16) unsigned short m2u[16][520];
  __shared__ __align__(16) unsigned short doL[32][520];
  __shared__ __align__(16) float dred[4][16][32];
  __shared__ float red[32], coefl[32], bsufl[32];
  __shared__ int lastf;
  float* slab = ws + OFF_SLAB + ((size_t)c*B_+b)*SLABSTR;
  // stage M2^T tile (independent of k3 phase)
  #pragma unroll
  for(int q=0;q<4;q++){
    int idx = tid + q*256; int d = idx>>1, half = idx&1;
    uint4 v = *(const uint4*)(bmw2 + ((size_t)(b*D_+d))*1024 + i0 + half*8);
    unsigned short tmp[8]; *(uint4*)tmp = v;
    #pragma unroll
    for(int jj=0;jj<8;jj++) m2u[half*8+jj][d] = tmp[jj];
  }
  if(tid<32) red[tid]=0.f;
  int w = tid>>6, lane = tid&63;
  // ---- k3 phase: wave w handles tokens w*8 .. w*8+7 ----
  {
    const float* lrow = ws + OFF_MLN + (size_t)b*512;
    float l8[8];
    *(float4*)&l8[0] = *(const float4*)(lrow + lane*8);
    *(float4*)&l8[4] = *(const float4*)(lrow + lane*8 + 4);
    for(int tt=0; tt<8; tt++){
      int t = w*8 + tt;
      int tok = b*S_ + c*32 + t;
      const float* orow = ws + OFF_OB + ((size_t)(b*32+t))*512;
      const float* krow = ws + OFF_K + (size_t)tok*512;
      const float* vrow = ws + OFF_V + (size_t)tok*512;
      float th = ws[OFF_TH + tok];
      float o8[8], k8[8], v8[8];
      *(float4*)&o8[0] = *(const float4*)(orow+lane*8); *(float4*)&o8[4] = *(const float4*)(orow+lane*8+4);
      *(float4*)&k8[0] = *(const float4*)(krow+lane*8); *(float4*)&k8[4] = *(const float4*)(krow+lane*8+4);
      *(float4*)&v8[0] = *(const float4*)(vrow+lane*8); *(float4*)&v8[4] = *(const float4*)(vrow+lane*8+4);
      float ss = 0.f;
      #pragma unroll
      for(int j=0;j<8;j++) ss += o8[j]*o8[j];
      float mu = wred(ss)*(1.f/512.f);
      float n = rsqrtf(mu + 1e-6f);
      float c2 = 2.f*th*(1.f/512.f);
      float u8[8]; float s1p = 0.f;
      #pragma unroll
      for(int j=0;j<8;j++){
        u8[j] = c2*(k8[j] + o8[j]*n*l8[j] - v8[j]);
        s1p += u8[j]*l8[j]*o8[j];
      }
      float s1 = wred(s1p);
      float fr = n*n*n*s1*(1.f/512.f);
      float do8[8], dln8[8]; float dd2=0.f, dl2=0.f;
      #pragma unroll
      for(int j=0;j<8;j++){
        do8[j]  = n*l8[j]*u8[j] - fr*o8[j];
        dln8[j] = u8[j]*o8[j]*n;
        dd2 += do8[j]*do8[j]; dl2 += dln8[j]*dln8[j];
      }
      float don2 = wred(dd2), dl2s = wred(dl2);
      *(uint4*)&doL[t][lane*8] = pck8(do8);
      if(bx==0){
        float* dlrow = ws + OFF_DLN + ((size_t)(b*32+t))*512;
        *(float4*)(dlrow+lane*8)   = *(float4*)&dln8[0];
        *(float4*)(dlrow+lane*8+4) = *(float4*)&dln8[4];
        unsigned short* dotw = (unsigned short*)(ws + OFF_DOT);
        #pragma unroll
        for(int j=0;j<8;j++)
          dotw[((size_t)(b*D_ + lane*8 + j))*32 + t] = f2bfu(do8[j]);
        if(lane==0){ atomicAdd(&slab[64+t], don2); atomicAdd(&slab[96+t], dl2s); }
      }
    }
  }
  __syncthreads();
  // ---- k4 GEMM: dh = M2^T do (do from LDS) ----
  int col = lane&15, lg = lane>>4;
  f4v acc0 = {0.f,0.f,0.f,0.f}, acc1 = {0.f,0.f,0.f,0.f};
  #pragma unroll
  for(int ks=0;ks<4;ks++){
    int k0 = w*128 + ks*32;
    s8v mA  = __builtin_bit_cast(s8v, *(const uint4*)&m2u[col][k0 + lg*8]);
    s8v dB0 = __builtin_bit_cast(s8v, *(const uint4*)&doL[col][k0 + lg*8]);
    s8v dB1 = __builtin_bit_cast(s8v, *(const uint4*)&doL[col+16][k0 + lg*8]);
    acc0 = __builtin_amdgcn_mfma_f32_16x16x32_bf16(mA, dB0, acc0, 0,0,0);
    acc1 = __builtin_amdgcn_mfma_f32_16x16x32_bf16(mA, dB1, acc1, 0,0,0);
  }
  #pragma unroll
  for(int j=0;j<4;j++){
    dred[w][lg*4+j][col]    = acc0[j];
    dred[w][lg*4+j][16+col] = acc1[j];
  }
  __syncthreads();
  #pragma unroll
  for(int e=0;e<2;e++){
    int idx = tid*2+e; int row = idx>>5, t = idx&31;
    float dh = dred[0][row][t]+dred[1][row][t]+dred[2][row][t]+dred[3][row][t];
    size_t zb = ((size_t)(b*I_ + i0 + row))*32 + t;
    float z = ws[OFF_Z1+zb];
    float s = 1.f/(1.f+expf(-z));
    float dp_ = dh * s*(1.f + z*(1.f-s));
    ws[OFF_DHP+zb] = dp_;
    atomicAdd(&red[t], dp_*dp_);
  }
  __syncthreads();
  if(tid<32) atomicAdd(&slab[32+tid], red[tid]);
  __threadfence();
  __syncthreads();
  if(tid==0){
    int* tick = (int*)(ws+OFF_TICK);
    lastf = (atomicAdd(&tick[c*B_+b],1) == 63) ? 1 : 0;
  }
  __syncthreads();
  if(!lastf) return;
  if(tid<32){
    float sqd = atomicAdd(&slab[32+tid], 0.f);
    float hn  = atomicAdd(&slab[0+tid], 0.f);
    float don2 = atomicAdd(&slab[64+tid], 0.f);
    float dl2  = atomicAdd(&slab[96+tid], 0.f);
    float kn2 = ws[OFF_KN2 + b*S_ + c*32 + tid];
    float sq = sqd*kn2 + don2*hn + dl2;
    coefl[tid] = fminf(1.f/(sqrtf(sq)+1e-6f), 1.f);
  }
  __syncthreads();
  if(tid==0){
    const float* eta = ws + OFF_ET + b*S_ + c*32;
    const float* alp = ws + OFF_AL + b*S_ + c*32;
    float Esuf=1.f, Bsuf=1.f, cu=1.f;
    for(int u=31;u>=0;u--){
      if(u<31){
        float e1 = eta[u+1], b1 = 1.f-alp[u+1];
        Esuf *= e1; Bsuf *= b1;
        cu = Bsuf + e1*cu;
      }
      bsufl[u]=Bsuf;
      slab[128+u] = Esuf*coefl[u];
      slab[160+u] = cu*coefl[u];
    }
    float PE = Esuf*eta[0];
    float PB = Bsuf*(1.f-alp[0]);
    float Q=0.f, Epre=1.f;
    for(int t2=0;t2<32;t2++){ Epre *= eta[t2]; Q += bsufl[t2]*Epre; }
    slab[192]=PE; slab[193]=PB; slab[194]=Q;
  }
}

// ---------------- R1 (MFMA): hq = silu(q @ M1^T), bf16 out ----------------
__global__ void __launch_bounds__(256) r1_gemm(float* __restrict__ ws){
  const unsigned short* qbf = (const unsigned short*)(ws + OFF_ORET + KBUF/2);
  const unsigned short* bmw1 = (const unsigned short*)(ws + OFF_BST) + STSZ;
  unsigned short* hqb = (unsigned short*)(ws + OFF_K);
  int b = blockIdx.z;
  int s0 = blockIdx.x*64, i0 = blockIdx.y*64;
  int w = threadIdx.x>>6, lane = threadIdx.x&63;
  int col = lane&15, lg = lane>>4;
  const unsigned short* qb = qbf + (size_t)b*S_*D_;
  const unsigned short* w1b = bmw1 + (size_t)b*I_*D_;
  f4v acc[4] = {{0,0,0,0},{0,0,0,0},{0,0,0,0},{0,0,0,0}};
  for(int k0=0;k0<512;k0+=32){
    s8v bB = __builtin_bit_cast(s8v, *(const uint4*)(w1b + (size_t)(i0 + w*16 + col)*512 + k0 + lg*8));
    #pragma unroll
    for(int rg=0;rg<4;rg++){
      s8v aA = __builtin_bit_cast(s8v, *(const uint4*)(qb + (size_t)(s0 + rg*16 + col)*512 + k0 + lg*8));
      acc[rg] = __builtin_amdgcn_mfma_f32_16x16x32_bf16(aA, bB, acc[rg], 0,0,0);
    }
  }
  unsigned short* hb = hqb + (size_t)b*S_*I_;
  #pragma unroll
  for(int rg=0;rg<4;rg++)
    #pragma unroll
    for(int j=0;j<4;j++){
      float z = acc[rg][j];
      hb[(size_t)(s0 + rg*16 + lg*4 + j)*1024 + i0 + w*16 + col] = f2bfu(z/(1.f+expf(-z)));
    }
}

// ---------------- R2 (MFMA): oret = hq @ M2^T ----------------
__global__ void __launch_bounds__(256) r2_gemm(float* __restrict__ ws){
  const unsigned short* hqb = (const unsigned short*)(ws + OFF_K);
  const unsigned short* bmw2 = (const unsigned short*)(ws + OFF_BST) + (size_t)3*STSZ;
  int b=blockIdx.z;
  int s0=blockIdx.x*64, d0=blockIdx.y*64;
  int w = threadIdx.x>>6, lane = threadIdx.x&63;
  int col = lane&15, lg = lane>>4;
  const unsigned short* hb = hqb + (size_t)b*S_*I_;
  const unsigned short* w2b = bmw2 + (size_t)b*D_*I_;
  f4v acc[4] = {{0,0,0,0},{0,0,0,0},{0,0,0,0},{0,0,0,0}};
  for(int k0=0;k0<1024;k0+=32){
    s8v bB = __builtin_bit_cast(s8v, *(const uint4*)(w2b + (size_t)(d0 + w*16 + col)*1024 + k0 + lg*8));
    #pragma unroll
    for(int rg=0;rg<4;rg++){
      s8v aA = __builtin_bit_cast(s8v, *(const uint4*)(hb + (size_t)(s0 + rg*16 + col)*1024 + k0 + lg*8));
      acc[rg] = __builtin_amdgcn_mfma_f32_16x16x32_bf16(aA, bB, acc[rg], 0,0,0);
    }
  }
  float* od = ws + OFF_ORET + (size_t)b*S_*D_;
  #pragma unroll
  for(int rg=0;rg<4;rg++)
    #pragma unroll
    for(int j=0;j<4;j++)
      od[(size_t)(s0 + rg*16 + lg*4 + j)*512 + d0 + w*16 + col] = acc[rg][j];
}

// ---------------- R3: out = q + rms(oret, Mln) ----------------
__global__ void __launch_bounds__(256) r3_out(float* __restrict__ ws, void* __restrict__ out){
  int f = ((const int*)(ws+OFF_FLAG))[0];
  int tok=blockIdx.x, tid=threadIdx.x;
  int b = tok >> 9;
  __shared__ float sm[8];
  const float* orow = ws + OFF_ORET + (size_t)tok*512;
  const float* qrow = ws + OFF_Q + (size_t)tok*512;
  const float* lrow = ws + OFF_MLN + (size_t)b*512;
  float o1=orow[tid], o2=orow[tid+256];
  float mu = blockReduceSum(o1*o1+o2*o2, sm)*(1.f/512.f);
  float n = rsqrtf(mu+1e-6f);
  float r1v = qrow[tid]     + o1*n*lrow[tid];
  float r2v = qrow[tid+256] + o2*n*lrow[tid+256];
  if(f){
    ((float*)out)[(size_t)tok*512+tid]     = r1v;
    ((float*)out)[(size_t)tok*512+tid+256] = r2v;
  } else {
    ((__hip_bfloat16*)out)[(size_t)tok*512+tid]     = __float2bfloat16(r1v);
    ((__hip_bfloat16*)out)[(size_t)tok*512+tid+256] = __float2bfloat16(r2v);
  }
}

extern "C" void kernel_launch(void* const* d_in, const int* in_sizes, int n_in,
                              void* d_out, int out_size, void* d_ws, size_t ws_size,
                              hipStream_t stream) {
  const void* x  = d_in[0];
  const void* wq = d_in[1];
  const void* wk = d_in[2];
  const void* wv = d_in[3];
  const void* qn = d_in[4];
  const void* kn = d_in[5];
  const void* aw = d_in[6];
  const void* tw = d_in[7];
  const void* ew = d_in[8];
  const void* w1 = d_in[9];
  const void* w2 = d_in[10];
  const void* ln = d_in[11];
  float* ws = (float*)d_ws;

  d0_detect<<<1,64,0,stream>>>(x, ws);
  p0_init<<<2048,256,0,stream>>>(ws, w1, w2, ln, x, wk, wv, wq);
  p1a<<<dim3(32,8,3),256,0,stream>>>(ws);
  p1b<<<2048,256,0,stream>>>(x, kn, qn, aw, tw, ew, ws);
  tr_k<<<dim3(8,8,4),256,0,stream>>>(ws);
  for(int c=0;c<=16;c++){
    k1_w1<<<dim3(65,4),256,0,stream>>>(ws, c);
    k2_w2<<<dim3(32,4),256,0,stream>>>(ws, c);
    if(c<16) k34<<<dim3(64,4),256,0,stream>>>(ws, c);
  }
  r1_gemm<<<dim3(8,16,4),256,0,stream>>>(ws);
  r2_gemm<<<dim3(8,8,4),256,0,stream>>>(ws);
  r3_out<<<2048,256,0,stream>>>(ws, d_out);
}

// Round 7
// 1043.404 us; speedup vs baseline: 2.2407x; 1.3460x over previous
//
#include <hip/hip_runtime.h>
#include <hip/hip_bf16.h>

#define B_ 4
#define S_ 512
#define D_ 512
#define I_ 1024
#define C_ 32
#define NC_ 16

// ---- ws layout (float offsets) ----
#define KBUF (B_*S_*D_)
#define STSZ (B_*I_*D_)
#define HSZ  (B_*I_*C_)
#define DOSZ (B_*C_*D_)
#define OFF_K    0
#define OFF_V    (OFF_K + KBUF)
#define OFF_Q    (OFF_V + KBUF)
#define OFF_TH   (OFF_Q + KBUF)
#define OFF_AL   (OFF_TH + B_*S_)
#define OFF_ET   (OFF_AL + B_*S_)
#define OFF_KN2  (OFF_ET + B_*S_)
#define OFF_SLN  (OFF_KN2 + B_*S_)
#define OFF_MLN  (OFF_SLN + B_*D_)
#define OFF_H2   (OFF_MLN + B_*D_)
#define OFF_Z1   (OFF_H2 + 2*HSZ)
#define OFF_DHP  (OFF_Z1 + HSZ)
#define OFF_DO   (OFF_DHP + HSZ)
#define OFF_DLN  (OFF_DO + DOSZ)
#define OFF_OB   (OFF_DLN + DOSZ)
#define OFF_SLAB (OFF_OB + DOSZ)
#define SLABSTR  256
#define OFF_TICK (OFF_SLAB + NC_*B_*SLABSTR)
#define OFF_TK2  (OFF_TICK + 64)             // (reserved)
#define OFF_FLAG (OFF_TK2 + 128)
#define OFF_ORET (OFF_FLAG + 16)
#define OFF_BST  (OFF_ORET + KBUF)     // bf16 states start here (ushort*)
// bf16 state arrays (ushort element offsets within bst):
//   BSW1 = 0, BMW1 = STSZ, BSW2 = 2*STSZ, BMW2 = 3*STSZ
#define OFF_KBFf (OFF_BST + 2*STSZ)          // kbf[b][s][d] bf16 (KBUF ushorts)
#define OFF_KBTf (OFF_KBFf + KBUF/2)         // kbt[b][d][s] bf16 (KBUF ushorts)
#define OFF_HIT  (OFF_KBTf + KBUF/2)         // h [buf][b][i][t] bf16
#define OFF_HTI  (OFF_HIT + HSZ)             // h [buf][b][t][i] bf16
#define OFF_DOB  (OFF_HTI + HSZ)             // do [b][t][d] bf16
#define OFF_DOT  (OFF_DOB + DOSZ/2)          // do [b][d][t] bf16
// aliases (temporally disjoint):
//   xbf (bf16 x, pre-loop)        -> OFF_ORET lower half
//   qbf (bf16 q, from p1b)        -> OFF_ORET upper half (until r2 writes oret)
//   wbf (bf16 wk/wv/wq, pre-loop) -> OFF_KBFf region (tr_k overwrites after p1a)
//   hqb (bf16 hq, post-loop)      -> OFF_K region (k f32 dead after loop)

typedef __attribute__((ext_vector_type(8))) short s8v;    // 8 bf16 in 4 VGPR
typedef __attribute__((ext_vector_type(4))) float f4v;    // mfma C/D

__device__ __forceinline__ float bf2f(__hip_bfloat16 v){ return __bfloat162float(v); }
__device__ __forceinline__ float bfu2f(unsigned short u){ return __uint_as_float(((unsigned)u)<<16); }
__device__ __forceinline__ unsigned short f2bfu(float f){
  unsigned x = __float_as_uint(f);
  return (unsigned short)((x + 0x7FFFu + ((x>>16)&1u)) >> 16);
}
__device__ __forceinline__ float4 u42f4(ushort4 u){
  float4 r; r.x=bfu2f(u.x); r.y=bfu2f(u.y); r.z=bfu2f(u.z); r.w=bfu2f(u.w); return r;
}
__device__ __forceinline__ ushort4 f42u4(float4 v){
  ushort4 r; r.x=f2bfu(v.x); r.y=f2bfu(v.y); r.z=f2bfu(v.z); r.w=f2bfu(v.w); return r;
}
__device__ __forceinline__ float ldin(const void* p, size_t i, int f){
  return f ? ((const float*)p)[i] : bf2f(((const __hip_bfloat16*)p)[i]);
}
__device__ __forceinline__ float4 ld4g(const void* p, size_t i, int f){
  if(f) return ((const float4*)p)[i>>2];
  return u42f4(((const ushort4*)p)[i>>2]);
}
__device__ __forceinline__ void unp8(uint4 u, float* f){
  f[0]=bfu2f((unsigned short)(u.x&0xffffu)); f[1]=bfu2f((unsigned short)(u.x>>16));
  f[2]=bfu2f((unsigned short)(u.y&0xffffu)); f[3]=bfu2f((unsigned short)(u.y>>16));
  f[4]=bfu2f((unsigned short)(u.z&0xffffu)); f[5]=bfu2f((unsigned short)(u.z>>16));
  f[6]=bfu2f((unsigned short)(u.w&0xffffu)); f[7]=bfu2f((unsigned short)(u.w>>16));
}
__device__ __forceinline__ uint4 pck8(const float* f){
  uint4 u;
  u.x = (unsigned)f2bfu(f[0]) | ((unsigned)f2bfu(f[1])<<16);
  u.y = (unsigned)f2bfu(f[2]) | ((unsigned)f2bfu(f[3])<<16);
  u.z = (unsigned)f2bfu(f[4]) | ((unsigned)f2bfu(f[5])<<16);
  u.w = (unsigned)f2bfu(f[6]) | ((unsigned)f2bfu(f[7])<<16);
  return u;
}

__device__ __forceinline__ float blockReduceSum(float v, float* sm){
  #pragma unroll
  for(int o=32;o>0;o>>=1) v += __shfl_down(v,o,64);
  int wid = threadIdx.x>>6, lane = threadIdx.x&63;
  __syncthreads();
  if(lane==0) sm[wid]=v;
  __syncthreads();
  return sm[0]+sm[1]+sm[2]+sm[3];
}

__device__ __forceinline__ float2 blockReduceSum2(float a, float b, float* sm){
  #pragma unroll
  for(int o=32;o>0;o>>=1){ a += __shfl_down(a,o,64); b += __shfl_down(b,o,64); }
  int wid = threadIdx.x>>6, lane = threadIdx.x&63;
  __syncthreads();
  if(lane==0){ sm[wid]=a; sm[4+wid]=b; }
  __syncthreads();
  float2 r; r.x = sm[0]+sm[1]+sm[2]+sm[3]; r.y = sm[4]+sm[5]+sm[6]+sm[7];
  return r;
}

// ---------------- D0: runtime input-dtype detection ----------------
__global__ void d0_detect(const void* __restrict__ x, float* __restrict__ ws){
  __shared__ int cnt;
  if(threadIdx.x==0) cnt=0;
  __syncthreads();
  unsigned w = ((const unsigned*)x)[(size_t)threadIdx.x*931 + 17];
  int e = (w>>7)&0xFF;
  if(e>=110 && e<=140) atomicAdd(&cnt,1);
  __syncthreads();
  if(threadIdx.x==0) ((int*)(ws+OFF_FLAG))[0] = (cnt<32) ? 1 : 0;  // 1 => f32 inputs
}

// ---------------- P0: init states / slabs / ticks + cvt x,wk/wv/wq -> bf16 ----------------
__global__ void p0_init(float* __restrict__ ws, const void* __restrict__ w1,
                        const void* __restrict__ w2, const void* __restrict__ ln,
                        const void* __restrict__ x, const void* __restrict__ wk,
                        const void* __restrict__ wv, const void* __restrict__ wq){
  int f = ((const int*)(ws+OFF_FLAG))[0];
  unsigned short* bst = (unsigned short*)(ws + OFF_BST);
  size_t id = (size_t)blockIdx.x*blockDim.x + threadIdx.x;
  size_t stride = (size_t)gridDim.x*blockDim.x;
  ushort4 z4 = {0,0,0,0};
  for(size_t t4=id; t4<(size_t)(STSZ/4); t4+=stride){
    size_t e4 = t4 % (size_t)(I_*D_/4);
    *(ushort4*)(bst + (size_t)STSZ + t4*4)   = f42u4(ld4g(w1, e4*4, f));  // BMW1
    *(ushort4*)(bst + (size_t)3*STSZ + t4*4) = f42u4(ld4g(w2, e4*4, f));  // BMW2
    *(ushort4*)(bst + t4*4) = z4;                                          // BSW1
    *(ushort4*)(bst + (size_t)2*STSZ + t4*4) = z4;                         // BSW2
  }
  unsigned short* xbf = (unsigned short*)(ws + OFF_ORET);
  unsigned short* wbf = (unsigned short*)(ws + OFF_KBFf);
  for(size_t t4=id; t4<(size_t)(KBUF/4); t4+=stride)
    *(ushort4*)(xbf + t4*4) = f42u4(ld4g(x, t4*4, f));
  for(size_t t4=id; t4<(size_t)(3*D_*D_/4); t4+=stride){
    int pid = (int)(t4 / (D_*D_/4));
    size_t e4 = t4 % (size_t)(D_*D_/4);
    const void* W = (pid==0)?wk:((pid==1)?wv:wq);
    *(ushort4*)(wbf + t4*4) = f42u4(ld4g(W, e4*4, f));
  }
  for(size_t t=id; t<(size_t)(B_*D_); t+=stride){
    ws[OFF_MLN+t] = ldin(ln,t % D_,f);
    ws[OFF_SLN+t] = 0.f;
  }
  for(size_t t=id; t<(size_t)(NC_*B_*SLABSTR); t+=stride) ws[OFF_SLAB+t]=0.f;
  int* tick = (int*)(ws + OFF_TICK);
  for(size_t t=id; t<192; t+=stride) tick[t]=0;
}

// ---------------- P1a (MFMA): k,v,q = silu(x@W^T) ----------------
// grid dim3(32,8,3): blockIdx.x spans ALL B*S = 2048 rows / 64
__global__ void __launch_bounds__(256) p1a(float* __restrict__ ws){
  const unsigned short* xbf = (const unsigned short*)(ws + OFF_ORET);
  const unsigned short* wbf = (const unsigned short*)(ws + OFF_KBFf);
  int pid = blockIdx.z;
  float* outp = ws + ((pid==0)?OFF_K:((pid==1)?OFF_V:OFF_Q));
  const unsigned short* W = wbf + (size_t)pid*D_*D_;
  int r0 = blockIdx.x*64, j0 = blockIdx.y*64;
  int w = threadIdx.x>>6, lane = threadIdx.x&63;
  int col = lane&15, lg = lane>>4;
  f4v acc[4] = {{0,0,0,0},{0,0,0,0},{0,0,0,0},{0,0,0,0}};
  for(int k0=0;k0<512;k0+=32){
    s8v bB = __builtin_bit_cast(s8v, *(const uint4*)(W + (size_t)(j0 + w*16 + col)*512 + k0 + lg*8));
    #pragma unroll
    for(int rg=0;rg<4;rg++){
      s8v aA = __builtin_bit_cast(s8v, *(const uint4*)(xbf + (size_t)(r0 + rg*16 + col)*512 + k0 + lg*8));
      acc[rg] = __builtin_amdgcn_mfma_f32_16x16x32_bf16(aA, bB, acc[rg], 0,0,0);
    }
  }
  #pragma unroll
  for(int rg=0;rg<4;rg++)
    #pragma unroll
    for(int j=0;j<4;j++){
      float z = acc[rg][j];
      outp[(size_t)(r0 + rg*16 + lg*4 + j)*512 + j0 + w*16 + col] = z/(1.f+expf(-z));
    }
}

// ---------------- P1b: rms(k),rms(q)(+bf16 q), |k|^2, gates ----------------
__global__ void __launch_bounds__(256) p1b(const void* __restrict__ x,
                    const void* __restrict__ kn,
                    const void* __restrict__ qn,
                    const void* __restrict__ aw,
                    const void* __restrict__ tw,
                    const void* __restrict__ ew,
                    float* __restrict__ ws){
  int f = ((const int*)(ws+OFF_FLAG))[0];
  int tok = blockIdx.x; int tid = threadIdx.x;
  __shared__ float sm[8];
  float* krow = ws + OFF_K + (size_t)tok*512;
  float* qrow = ws + OFF_Q + (size_t)tok*512;
  float a = krow[tid], b = krow[tid+256];
  float ss = blockReduceSum(a*a+b*b, sm);
  float n = rsqrtf(ss*(1.f/512.f) + 1e-6f);
  float k1v = a*n*ldin(kn,tid,f);
  float k2v = b*n*ldin(kn,tid+256,f);
  krow[tid]=k1v; krow[tid+256]=k2v;
  float kn2 = blockReduceSum(k1v*k1v+k2v*k2v, sm);
  if(tid==0) ws[OFF_KN2+tok]=kn2;
  a = qrow[tid]; b = qrow[tid+256];
  ss = blockReduceSum(a*a+b*b, sm);
  n = rsqrtf(ss*(1.f/512.f)+1e-6f);
  float q1 = a*n*ldin(qn,tid,f);
  float q2 = b*n*ldin(qn,tid+256,f);
  qrow[tid]=q1; qrow[tid+256]=q2;
  unsigned short* qbf = (unsigned short*)(ws + OFF_ORET + KBUF/2);
  qbf[(size_t)tok*512+tid]     = f2bfu(q1);
  qbf[(size_t)tok*512+tid+256] = f2bfu(q2);
  float x1=ldin(x,(size_t)tok*512+tid,f), x2=ldin(x,(size_t)tok*512+tid+256,f);
  float td = blockReduceSum(x1*ldin(tw,tid,f) + x2*ldin(tw,tid+256,f), sm);
  float ad = blockReduceSum(x1*ldin(aw,tid,f) + x2*ldin(aw,tid+256,f), sm);
  float ed = blockReduceSum(x1*ldin(ew,tid,f) + x2*ldin(ew,tid+256,f), sm);
  if(tid==0){
    ws[OFF_TH+tok] = 0.01f/(1.f+expf(-td));
    ws[OFF_AL+tok] = 1.f/(1.f+expf(-ad));
    ws[OFF_ET+tok] = 1.f/(1.f+expf(-ed));
  }
}

// ---------------- TRK: snapshot normalized K as bf16, both orientations ----------------
__global__ void __launch_bounds__(256) tr_k(float* __restrict__ ws){
  unsigned short* kbf = (unsigned short*)(ws + OFF_KBFf);
  unsigned short* kbt = (unsigned short*)(ws + OFF_KBTf);
  int b = blockIdx.z, st = blockIdx.y, dt = blockIdx.x;
  int s0 = st*64, d0 = dt*64;
  __shared__ unsigned short t[64][72];
  int tid = threadIdx.x;
  #pragma unroll
  for(int q=0;q<4;q++){
    int idx = tid + q*256; int r = idx>>4, cq = idx&15;
    float4 v = *(const float4*)(ws + OFF_K + ((size_t)(b*512 + s0 + r))*512 + d0 + cq*4);
    ushort4 u; u.x=f2bfu(v.x); u.y=f2bfu(v.y); u.z=f2bfu(v.z); u.w=f2bfu(v.w);
    *(ushort4*)&t[r][cq*4] = u;
    *(ushort4*)(kbf + ((size_t)(b*512 + s0 + r))*512 + d0 + cq*4) = u;
  }
  __syncthreads();
  #pragma unroll
  for(int q=0;q<4;q++){
    int idx = tid + q*256; int d = idx>>4, sq = idx&15;
    ushort4 u; u.x=t[sq*4+0][d]; u.y=t[sq*4+1][d]; u.z=t[sq*4+2][d]; u.w=t[sq*4+3][d];
    *(ushort4*)(kbt + ((size_t)(b*512 + d0 + d))*512 + s0 + sq*4) = u;
  }
}

// ---------------- K1 (MFMA): update W1(+ln) w/ chunk c-1 grads; z,h for chunk c ----------------
__global__ void __launch_bounds__(256) k1_w1(float* __restrict__ ws, int c){
  unsigned short* bsw1 = (unsigned short*)(ws + OFF_BST);
  unsigned short* bmw1 = bsw1 + STSZ;
  const unsigned short* kbf = (const unsigned short*)(ws + OFF_KBFf);
  const unsigned short* kbt = (const unsigned short*)(ws + OFF_KBTf);
  int b = blockIdx.y, bx = blockIdx.x, tid = threadIdx.x;
  __shared__ float sE[32], sC[32], scal[3];
  if(c>0){
    const float* slab = ws + OFF_SLAB + ((long)(c-1)*B_ + b)*SLABSTR;
    if(tid<32){ sE[tid]=slab[128+tid]; sC[tid]=slab[160+tid]; }
    if(tid>=32 && tid<35) scal[tid-32]=slab[192+(tid-32)];
  }
  __syncthreads();
  float PE = c>0? scal[0]:1.f, PB = c>0? scal[1]:1.f, Q = c>0? scal[2]:0.f;
  if(bx==64){
    if(c>0){
      for(int d=tid; d<512; d+=256){
        float gE=0,gC=0;
        for(int u=0;u<32;u++){
          float dl = ws[OFF_DLN + ((size_t)(b*32+u))*512 + d];
          gE += sE[u]*dl; gC += sC[u]*dl;
        }
        size_t ix = OFF_SLN + (size_t)b*512 + d;
        float sv=ws[ix], mv=ws[ix + (OFF_MLN-OFF_SLN)];
        ws[ix] = PE*sv - gE;
        ws[ix + (OFF_MLN-OFF_SLN)] = PB*mv + Q*sv - gC;
      }
    }
    return;
  }
  __shared__ __align__(16) float gbf[4][2][16][36];
  __shared__ __align__(16) unsigned short ztile[4][16][40];
  __shared__ __align__(16) float zred[4][16][32];
  __shared__ float hredL[32];
  int w = tid>>6, lane = tid&63;
  int i0 = bx*16;
  int col = lane&15, lg = lane>>4;
  int rr = lane>>2, c0 = (lane&3)*8;
  s8v aE = {}, aC = {};
  if(c>0){
    const float* dp = ws + OFF_DHP + ((size_t)(b*I_ + i0 + col))*32 + lg*8;
    float4 dv0 = *(const float4*)dp;
    float4 dv1 = *(const float4*)(dp+4);
    float dv[8] = {dv0.x,dv0.y,dv0.z,dv0.w,dv1.x,dv1.y,dv1.z,dv1.w};
    #pragma unroll
    for(int j=0;j<8;j++){
      aE[j] = (short)f2bfu(sE[lg*8+j]*dv[j]);
      aC[j] = (short)f2bfu(sC[lg*8+j]*dv[j]);
    }
  }
  f4v zacc0 = {0.f,0.f,0.f,0.f}, zacc1 = {0.f,0.f,0.f,0.f};
  const int d0w = w*128;
  const size_t srowbase = ((size_t)(b*I_ + i0))*512;
  const size_t kprow = (size_t)(c-1)*32;
  for(int sl=0; sl<4; sl++){
    int dbase = d0w + sl*32;
    size_t gaddr = srowbase + (size_t)rr*512 + dbase + c0;
    if(c>0){
      #pragma unroll
      for(int t2=0;t2<2;t2++){
        int dt = dbase + t2*16;
        const unsigned short* kp = kbt + ((size_t)(b*512 + dt + col))*512 + kprow + lg*8;
        s8v kB = __builtin_bit_cast(s8v, *(const uint4*)kp);
        f4v zero4 = {0.f,0.f,0.f,0.f};
        f4v gE4 = __builtin_amdgcn_mfma_f32_16x16x32_bf16(aE, kB, zero4, 0,0,0);
        f4v gC4 = __builtin_amdgcn_mfma_f32_16x16x32_bf16(aC, kB, zero4, 0,0,0);
        #pragma unroll
        for(int j=0;j<4;j++){
          gbf[w][0][lg*4+j][t2*16+col] = gE4[j];
          gbf[w][1][lg*4+j][t2*16+col] = gC4[j];
        }
      }
      uint4 su = *(uint4*)(bsw1 + gaddr);
      uint4 mu = *(uint4*)(bmw1 + gaddr);
      float s8[8], m8[8];
      unp8(su, s8); unp8(mu, m8);
      float ns[8], nmv[8];
      #pragma unroll
      for(int j=0;j<8;j++){
        float ge = gbf[w][0][rr][c0+j];
        float gc = gbf[w][1][rr][c0+j];
        ns[j]  = PE*s8[j] - ge;
        nmv[j] = PB*m8[j] + Q*s8[j] - gc;
      }
      *(uint4*)(bsw1 + gaddr) = pck8(ns);
      uint4 nmu = pck8(nmv);
      *(uint4*)(bmw1 + gaddr) = nmu;
      *(uint4*)&ztile[w][rr][c0] = nmu;
    } else {
      uint4 mu = *(uint4*)(bmw1 + gaddr);
      *(uint4*)&ztile[w][rr][c0] = mu;
    }
    if(c<16){
      s8v mA = __builtin_bit_cast(s8v, *(const uint4*)&ztile[w][col][lg*8]);
      const unsigned short* kc0 = kbf + ((size_t)(b*512 + c*32 + col))*512 + dbase + lg*8;
      s8v kB0 = __builtin_bit_cast(s8v, *(const uint4*)kc0);
      s8v kB1 = __builtin_bit_cast(s8v, *(const uint4*)(kc0 + (size_t)16*512));
      zacc0 = __builtin_amdgcn_mfma_f32_16x16x32_bf16(mA, kB0, zacc0, 0,0,0);
      zacc1 = __builtin_amdgcn_mfma_f32_16x16x32_bf16(mA, kB1, zacc1, 0,0,0);
    }
  }
  if(c<16){
    #pragma unroll
    for(int j=0;j<4;j++){
      zred[w][lg*4+j][col]    = zacc0[j];
      zred[w][lg*4+j][16+col] = zacc1[j];
    }
    if(tid<32) hredL[tid]=0.f;
    __syncthreads();
    unsigned short* hit = (unsigned short*)(ws + OFF_HIT) + (size_t)(c&1)*HSZ;
    unsigned short* hti = (unsigned short*)(ws + OFF_HTI) + (size_t)(c&1)*HSZ;
    #pragma unroll
    for(int e=0;e<2;e++){
      int idx = tid*2+e; int row = idx>>5, t = idx&31;
      float z = zred[0][row][t]+zred[1][row][t]+zred[2][row][t]+zred[3][row][t];
      size_t zb = ((size_t)(b*I_ + i0 + row))*32 + t;
      ws[OFF_Z1+zb] = z;
      float h = z/(1.f+expf(-z));
      unsigned short hb = f2bfu(h);
      hit[zb] = hb;
      hti[((size_t)(b*C_+t))*I_ + i0 + row] = hb;
      atomicAdd(&hredL[t], h*h);
    }
    __syncthreads();
    if(tid<32) atomicAdd(ws + OFF_SLAB + ((size_t)c*B_ + b)*SLABSTR + tid, hredL[tid]);
  }
}

// ---------------- K2 (MFMA): update W2 w/ chunk c-1 grads; o = M2@h_c ----------------
__global__ void __launch_bounds__(256) k2_w2(float* __restrict__ ws, int c){
  unsigned short* bsw2 = (unsigned short*)(ws + OFF_BST) + (size_t)2*STSZ;
  unsigned short* bmw2 = bsw2 + STSZ;
  const unsigned short* hitp = (const unsigned short*)(ws + OFF_HIT) + (size_t)((c-1)&1)*HSZ;
  const unsigned short* htic = (const unsigned short*)(ws + OFF_HTI) + (size_t)(c&1)*HSZ;
  const unsigned short* dotb = (const unsigned short*)(ws + OFF_DOT);
  int b = blockIdx.y, bx = blockIdx.x, tid = threadIdx.x;
  int d0 = bx*16;
  __shared__ float sE[32], sC[32], scal[3];
  __shared__ __align__(16) float gbf[4][2][16][36];
  __shared__ __align__(16) unsigned short ztile[4][16][40];
  __shared__ __align__(16) float ored[4][16][32];
  if(c>0){
    const float* slab = ws + OFF_SLAB + ((long)(c-1)*B_+b)*SLABSTR;
    if(tid<32){ sE[tid]=slab[128+tid]; sC[tid]=slab[160+tid]; }
    if(tid>=32&&tid<35) scal[tid-32]=slab[192+tid-32];
  }
  __syncthreads();
  float PE = c>0?scal[0]:1.f, PB=c>0?scal[1]:1.f, Q=c>0?scal[2]:0.f;
  int w = tid>>6, lane = tid&63;
  int col = lane&15, lg = lane>>4;
  int rr = lane>>2, c0 = (lane&3)*8;
  s8v aE = {}, aC = {};
  if(c>0){
    const unsigned short* dp = dotb + ((size_t)(b*D_ + d0 + col))*32 + lg*8;
    float dv[8]; unp8(*(const uint4*)dp, dv);
    #pragma unroll
    for(int j=0;j<8;j++){
      aE[j] = (short)f2bfu(sE[lg*8+j]*dv[j]);
      aC[j] = (short)f2bfu(sC[lg*8+j]*dv[j]);
    }
  }
  f4v oacc0 = {0.f,0.f,0.f,0.f}, oacc1 = {0.f,0.f,0.f,0.f};
  const size_t srowbase = ((size_t)(b*D_ + d0))*1024;
  size_t ga0 = srowbase + (size_t)rr*1024 + w*256 + c0;
  uint4 su={0,0,0,0}, mu, svn=su, mvn;
  if(c>0) su = *(uint4*)(bsw2 + ga0);
  mu = *(uint4*)(bmw2 + ga0);
  for(int sl=0; sl<8; sl++){
    int ibase = w*256 + sl*32;
    size_t gaddr = srowbase + (size_t)rr*1024 + ibase + c0;
    if(sl<7){
      if(c>0) svn = *(uint4*)(bsw2 + gaddr + 32);
      mvn = *(uint4*)(bmw2 + gaddr + 32);
    }
    if(c>0){
      #pragma unroll
      for(int t2=0;t2<2;t2++){
        const unsigned short* hp = hitp + ((size_t)(b*I_ + ibase + t2*16 + col))*32 + lg*8;
        s8v hB = __builtin_bit_cast(s8v, *(const uint4*)hp);
        f4v zero4 = {0.f,0.f,0.f,0.f};
        f4v gE4 = __builtin_amdgcn_mfma_f32_16x16x32_bf16(aE, hB, zero4, 0,0,0);
        f4v gC4 = __builtin_amdgcn_mfma_f32_16x16x32_bf16(aC, hB, zero4, 0,0,0);
        #pragma unroll
        for(int j=0;j<4;j++){
          gbf[w][0][lg*4+j][t2*16+col] = gE4[j];
          gbf[w][1][lg*4+j][t2*16+col] = gC4[j];
        }
      }
      float s8[8], m8[8];
      unp8(su, s8); unp8(mu, m8);
      float ns[8], nmv[8];
      #pragma unroll
      for(int j=0;j<8;j++){
        ns[j]  = PE*s8[j] - gbf[w][0][rr][c0+j];
        nmv[j] = PB*m8[j] + Q*s8[j] - gbf[w][1][rr][c0+j];
      }
      *(uint4*)(bsw2 + gaddr) = pck8(ns);
      uint4 nmu = pck8(nmv);
      *(uint4*)(bmw2 + gaddr) = nmu;
      *(uint4*)&ztile[w][rr][c0] = nmu;
    } else {
      *(uint4*)&ztile[w][rr][c0] = mu;
    }
    if(c<16){
      s8v mA = __builtin_bit_cast(s8v, *(const uint4*)&ztile[w][col][lg*8]);
      const unsigned short* hb = htic + ((size_t)(b*C_+col))*I_ + ibase + lg*8;
      s8v hB0 = __builtin_bit_cast(s8v, *(const uint4*)hb);
      s8v hB1 = __builtin_bit_cast(s8v, *(const uint4*)(hb + (size_t)16*I_));
      oacc0 = __builtin_amdgcn_mfma_f32_16x16x32_bf16(mA, hB0, oacc0, 0,0,0);
      oacc1 = __builtin_amdgcn_mfma_f32_16x16x32_bf16(mA, hB1, oacc1, 0,0,0);
    }
    su = svn; mu = mvn;
  }
  if(c<16){
    #pragma unroll
    for(int j=0;j<4;j++){
      ored[w][lg*4+j][col]    = oacc0[j];
      ored[w][lg*4+j][16+col] = oacc1[j];
    }
    __syncthreads();
    #pragma unroll
    for(int e=0;e<2;e++){
      int idx = tid*2+e; int row = idx>>5, t = idx&31;
      float o = ored[0][row][t]+ored[1][row][t]+ored[2][row][t]+ored[3][row][t];
      ws[OFF_OB + ((size_t)(b*C_+t))*512 + d0 + row] = o;
    }
  }
}

// ---------------- K3: per-token rms backward ----------------
__global__ void __launch_bounds__(256) k3_rms(float* __restrict__ ws, int c){
  int t = blockIdx.x, b = blockIdx.y, tid=threadIdx.x;
  __shared__ float sm[8];
  int tok = b*S_ + c*32 + t;
  const float* orow = ws + OFF_OB + ((size_t)(b*32+t))*512;
  const float* krow = ws + OFF_K + (size_t)tok*512;
  const float* vrow = ws + OFF_V + (size_t)tok*512;
  const float* lrow = ws + OFF_MLN + (size_t)b*512;
  float th = ws[OFF_TH + tok];
  float o1=orow[tid], o2=orow[tid+256];
  float mu = blockReduceSum(o1*o1+o2*o2, sm)*(1.f/512.f);
  float n = rsqrtf(mu + 1e-6f);
  float l1=lrow[tid], l2=lrow[tid+256];
  float k1=krow[tid], k2=krow[tid+256];
  float v1=vrow[tid], v2=vrow[tid+256];
  float c2 = 2.f*th*(1.f/512.f);
  float u1 = c2*(k1 + o1*n*l1 - v1);
  float u2 = c2*(k2 + o2*n*l2 - v2);
  float s1 = blockReduceSum(u1*l1*o1 + u2*l2*o2, sm);
  float dln1 = u1*o1*n, dln2v = u2*o2*n;
  float f = n*n*n*s1*(1.f/512.f);
  float do1 = n*l1*u1 - f*o1;
  float do2 = n*l2*u2 - f*o2;
  float2 dd = blockReduceSum2(do1*do1+do2*do2, dln1*dln1+dln2v*dln2v, sm);
  float* dlrow = ws + OFF_DLN + ((size_t)(b*32+t))*512;
  dlrow[tid]=dln1; dlrow[tid+256]=dln2v;
  unsigned short* dob = (unsigned short*)(ws + OFF_DOB);
  unsigned short* dotb = (unsigned short*)(ws + OFF_DOT);
  dob[((size_t)(b*C_+t))*512 + tid]       = f2bfu(do1);
  dob[((size_t)(b*C_+t))*512 + tid + 256] = f2bfu(do2);
  dotb[((size_t)(b*D_ + tid))*32 + t]       = f2bfu(do1);
  dotb[((size_t)(b*D_ + tid + 256))*32 + t] = f2bfu(do2);
  if(tid==0){
    float* slab = ws + OFF_SLAB + ((size_t)c*B_+b)*SLABSTR;
    slab[64+t]=dd.x; slab[96+t]=dd.y;
  }
}

// ---------------- K4 (MFMA): dh = M2^T do, dhp, grad-norm + scan scalars ----------------
__global__ void __launch_bounds__(256) k4_dh(float* __restrict__ ws, int c){
  unsigned short* bmw2 = (unsigned short*)(ws + OFF_BST) + (size_t)3*STSZ;
  const unsigned short* dob = (const unsigned short*)(ws + OFF_DOB);
  int bx = blockIdx.x, b = blockIdx.y, tid = threadIdx.x;
  int i0 = bx*16;
  __shared__ __align__(16) unsigned short m2u[16][520];
  __shared__ __align__(16) float dred[4][16][32];
  __shared__ float red[32], coefl[32], bsufl[32];
  __shared__ int lastf;
  #pragma unroll
  for(int q=0;q<4;q++){
    int idx = tid + q*256; int d = idx>>1, half = idx&1;
    uint4 v = *(const uint4*)(bmw2 + ((size_t)(b*D_+d))*1024 + i0 + half*8);
    unsigned short tmp[8]; *(uint4*)tmp = v;
    #pragma unroll
    for(int jj=0;jj<8;jj++) m2u[half*8+jj][d] = tmp[jj];
  }
  if(tid<32) red[tid]=0.f;
  __syncthreads();
  int w = tid>>6, lane = tid&63;
  int col = lane&15, lg = lane>>4;
  f4v acc0 = {0.f,0.f,0.f,0.f}, acc1 = {0.f,0.f,0.f,0.f};
  #pragma unroll
  for(int ks=0;ks<4;ks++){
    int k0 = w*128 + ks*32;
    s8v mA = __builtin_bit_cast(s8v, *(const uint4*)&m2u[col][k0 + lg*8]);
    const unsigned short* dp = dob + ((size_t)(b*C_+col))*512 + k0 + lg*8;
    s8v dB0 = __builtin_bit_cast(s8v, *(const uint4*)dp);
    s8v dB1 = __builtin_bit_cast(s8v, *(const uint4*)(dp + (size_t)16*512));
    acc0 = __builtin_amdgcn_mfma_f32_16x16x32_bf16(mA, dB0, acc0, 0,0,0);
    acc1 = __builtin_amdgcn_mfma_f32_16x16x32_bf16(mA, dB1, acc1, 0,0,0);
  }
  #pragma unroll
  for(int j=0;j<4;j++){
    dred[w][lg*4+j][col]    = acc0[j];
    dred[w][lg*4+j][16+col] = acc1[j];
  }
  __syncthreads();
  #pragma unroll
  for(int e=0;e<2;e++){
    int idx = tid*2+e; int row = idx>>5, t = idx&31;
    float dh = dred[0][row][t]+dred[1][row][t]+dred[2][row][t]+dred[3][row][t];
    size_t zb = ((size_t)(b*I_ + i0 + row))*32 + t;
    float z = ws[OFF_Z1+zb];
    float s = 1.f/(1.f+expf(-z));
    float dp_ = dh * s*(1.f + z*(1.f-s));
    ws[OFF_DHP+zb] = dp_;
    atomicAdd(&red[t], dp_*dp_);
  }
  __syncthreads();
  float* slab = ws + OFF_SLAB + ((size_t)c*B_+b)*SLABSTR;
  if(tid<32) atomicAdd(&slab[32+tid], red[tid]);
  __threadfence();
  __syncthreads();
  if(tid==0){
    int* tick = (int*)(ws+OFF_TICK);
    lastf = (atomicAdd(&tick[c*B_+b],1) == 63) ? 1 : 0;
  }
  __syncthreads();
  if(!lastf) return;
  if(tid<32){
    float sqd = atomicAdd(&slab[32+tid], 0.f);
    float hn  = atomicAdd(&slab[0+tid], 0.f);
    float don2 = slab[64+tid], dl2 = slab[96+tid];
    float kn2 = ws[OFF_KN2 + b*S_ + c*32 + tid];
    float sq = sqd*kn2 + don2*hn + dl2;
    coefl[tid] = fminf(1.f/(sqrtf(sq)+1e-6f), 1.f);
  }
  __syncthreads();
  if(tid==0){
    const float* eta = ws + OFF_ET + b*S_ + c*32;
    const float* alp = ws + OFF_AL + b*S_ + c*32;
    float Esuf=1.f, Bsuf=1.f, cu=1.f;
    for(int u=31;u>=0;u--){
      if(u<31){
        float e1 = eta[u+1], b1 = 1.f-alp[u+1];
        Esuf *= e1; Bsuf *= b1;
        cu = Bsuf + e1*cu;
      }
      bsufl[u]=Bsuf;
      slab[128+u] = Esuf*coefl[u];
      slab[160+u] = cu*coefl[u];
    }
    float PE = Esuf*eta[0];
    float PB = Bsuf*(1.f-alp[0]);
    float Q=0.f, Epre=1.f;
    for(int t2=0;t2<32;t2++){ Epre *= eta[t2]; Q += bsufl[t2]*Epre; }
    slab[192]=PE; slab[193]=PB; slab[194]=Q;
  }
}

// ---------------- R1 (MFMA): hq = silu(q @ M1^T), bf16 out ----------------
__global__ void __launch_bounds__(256) r1_gemm(float* __restrict__ ws){
  const unsigned short* qbf = (const unsigned short*)(ws + OFF_ORET + KBUF/2);
  const unsigned short* bmw1 = (const unsigned short*)(ws + OFF_BST) + STSZ;
  unsigned short* hqb = (unsigned short*)(ws + OFF_K);
  int b = blockIdx.z;
  int s0 = blockIdx.x*64, i0 = blockIdx.y*64;
  int w = threadIdx.x>>6, lane = threadIdx.x&63;
  int col = lane&15, lg = lane>>4;
  const unsigned short* qb = qbf + (size_t)b*S_*D_;
  const unsigned short* w1b = bmw1 + (size_t)b*I_*D_;
  f4v acc[4] = {{0,0,0,0},{0,0,0,0},{0,0,0,0},{0,0,0,0}};
  for(int k0=0;k0<512;k0+=32){
    s8v bB = __builtin_bit_cast(s8v, *(const uint4*)(w1b + (size_t)(i0 + w*16 + col)*512 + k0 + lg*8));
    #pragma unroll
    for(int rg=0;rg<4;rg++){
      s8v aA = __builtin_bit_cast(s8v, *(const uint4*)(qb + (size_t)(s0 + rg*16 + col)*512 + k0 + lg*8));
      acc[rg] = __builtin_amdgcn_mfma_f32_16x16x32_bf16(aA, bB, acc[rg], 0,0,0);
    }
  }
  unsigned short* hb = hqb + (size_t)b*S_*I_;
  #pragma unroll
  for(int rg=0;rg<4;rg++)
    #pragma unroll
    for(int j=0;j<4;j++){
      float z = acc[rg][j];
      hb[(size_t)(s0 + rg*16 + lg*4 + j)*1024 + i0 + w*16 + col] = f2bfu(z/(1.f+expf(-z)));
    }
}

// ---------------- R2 (MFMA): oret = hq @ M2^T ----------------
__global__ void __launch_bounds__(256) r2_gemm(float* __restrict__ ws){
  const unsigned short* hqb = (const unsigned short*)(ws + OFF_K);
  const unsigned short* bmw2 = (const unsigned short*)(ws + OFF_BST) + (size_t)3*STSZ;
  int b=blockIdx.z;
  int s0=blockIdx.x*64, d0=blockIdx.y*64;
  int w = threadIdx.x>>6, lane = threadIdx.x&63;
  int col = lane&15, lg = lane>>4;
  const unsigned short* hb = hqb + (size_t)b*S_*I_;
  const unsigned short* w2b = bmw2 + (size_t)b*D_*I_;
  f4v acc[4] = {{0,0,0,0},{0,0,0,0},{0,0,0,0},{0,0,0,0}};
  for(int k0=0;k0<1024;k0+=32){
    s8v bB = __builtin_bit_cast(s8v, *(const uint4*)(w2b + (size_t)(d0 + w*16 + col)*1024 + k0 + lg*8));
    #pragma unroll
    for(int rg=0;rg<4;rg++){
      s8v aA = __builtin_bit_cast(s8v, *(const uint4*)(hb + (size_t)(s0 + rg*16 + col)*1024 + k0 + lg*8));
      acc[rg] = __builtin_amdgcn_mfma_f32_16x16x32_bf16(aA, bB, acc[rg], 0,0,0);
    }
  }
  float* od = ws + OFF_ORET + (size_t)b*S_*D_;
  #pragma unroll
  for(int rg=0;rg<4;rg++)
    #pragma unroll
    for(int j=0;j<4;j++)
      od[(size_t)(s0 + rg*16 + lg*4 + j)*512 + d0 + w*16 + col] = acc[rg][j];
}

// ---------------- R3: out = q + rms(oret, Mln) ----------------
__global__ void __launch_bounds__(256) r3_out(float* __restrict__ ws, void* __restrict__ out){
  int f = ((const int*)(ws+OFF_FLAG))[0];
  int tok=blockIdx.x, tid=threadIdx.x;
  int b = tok >> 9;
  __shared__ float sm[8];
  const float* orow = ws + OFF_ORET + (size_t)tok*512;
  const float* qrow = ws + OFF_Q + (size_t)tok*512;
  const float* lrow = ws + OFF_MLN + (size_t)b*512;
  float o1=orow[tid], o2=orow[tid+256];
  float mu = blockReduceSum(o1*o1+o2*o2, sm)*(1.f/512.f);
  float n = rsqrtf(mu+1e-6f);
  float r1v = qrow[tid]     + o1*n*lrow[tid];
  float r2v = qrow[tid+256] + o2*n*lrow[tid+256];
  if(f){
    ((float*)out)[(size_t)tok*512+tid]     = r1v;
    ((float*)out)[(size_t)tok*512+tid+256] = r2v;
  } else {
    ((__hip_bfloat16*)out)[(size_t)tok*512+tid]     = __float2bfloat16(r1v);
    ((__hip_bfloat16*)out)[(size_t)tok*512+tid+256] = __float2bfloat16(r2v);
  }
}

extern "C" void kernel_launch(void* const* d_in, const int* in_sizes, int n_in,
                              void* d_out, int out_size, void* d_ws, size_t ws_size,
                              hipStream_t stream) {
  const void* x  = d_in[0];
  const void* wq = d_in[1];
  const void* wk = d_in[2];
  const void* wv = d_in[3];
  const void* qn = d_in[4];
  const void* kn = d_in[5];
  const void* aw = d_in[6];
  const void* tw = d_in[7];
  const void* ew = d_in[8];
  const void* w1 = d_in[9];
  const void* w2 = d_in[10];
  const void* ln = d_in[11];
  float* ws = (float*)d_ws;

  d0_detect<<<1,64,0,stream>>>(x, ws);
  p0_init<<<2048,256,0,stream>>>(ws, w1, w2, ln, x, wk, wv, wq);
  p1a<<<dim3(32,8,3),256,0,stream>>>(ws);
  p1b<<<2048,256,0,stream>>>(x, kn, qn, aw, tw, ew, ws);
  tr_k<<<dim3(8,8,4),256,0,stream>>>(ws);
  for(int c=0;c<=16;c++){
    k1_w1<<<dim3(65,4),256,0,stream>>>(ws, c);
    k2_w2<<<dim3(32,4),256,0,stream>>>(ws, c);
    if(c<16){
      k3_rms<<<dim3(32,4),256,0,stream>>>(ws, c);
      k4_dh<<<dim3(64,4),256,0,stream>>>(ws, c);
    }
  }
  r1_gemm<<<dim3(8,16,4),256,0,stream>>>(ws);
  r2_gemm<<<dim3(8,8,4),256,0,stream>>>(ws);
  r3_out<<<2048,256,0,stream>>>(ws, d_out);
}

// Round 8
// 1038.205 us; speedup vs baseline: 2.2519x; 1.0050x over previous
//
#include <hip/hip_runtime.h>
#include <hip/hip_bf16.h>

#define B_ 4
#define S_ 512
#define D_ 512
#define I_ 1024
#define C_ 32
#define NC_ 16

// ---- ws layout (float offsets) ----
#define KBUF (B_*S_*D_)
#define STSZ (B_*I_*D_)
#define HSZ  (B_*I_*C_)
#define DOSZ (B_*C_*D_)
#define OFF_K    0
#define OFF_V    (OFF_K + KBUF)
#define OFF_Q    (OFF_V + KBUF)
#define OFF_TH   (OFF_Q + KBUF)
#define OFF_AL   (OFF_TH + B_*S_)
#define OFF_ET   (OFF_AL + B_*S_)
#define OFF_KN2  (OFF_ET + B_*S_)
#define OFF_SLN  (OFF_KN2 + B_*S_)
#define OFF_MLN  (OFF_SLN + B_*D_)
#define OFF_H2   (OFF_MLN + B_*D_)
#define OFF_Z1   (OFF_H2 + 2*HSZ)
#define OFF_DHP  (OFF_Z1 + HSZ)
#define OFF_DO   (OFF_DHP + HSZ)
#define OFF_DLN  (OFF_DO + DOSZ)
#define OFF_OB   (OFF_DLN + DOSZ)
#define OFF_SLAB (OFF_OB + DOSZ)
#define SLABSTR  256
#define OFF_TICK (OFF_SLAB + NC_*B_*SLABSTR)
#define OFF_TK2  (OFF_TICK + 64)             // (reserved)
#define OFF_FLAG (OFF_TK2 + 128)
#define OFF_ORET (OFF_FLAG + 16)
#define OFF_BST  (OFF_ORET + KBUF)     // bf16 states start here (ushort*)
// bf16 state arrays (ushort element offsets within bst):
//   BSW1 = 0, BMW1 = STSZ, BSW2 = 2*STSZ, BMW2 = 3*STSZ
#define OFF_KBFf (OFF_BST + 2*STSZ)          // kbf[b][s][d] bf16 (KBUF ushorts)
#define OFF_KBTf (OFF_KBFf + KBUF/2)         // kbt[b][d][s] bf16 (KBUF ushorts)
#define OFF_HIT  (OFF_KBTf + KBUF/2)         // h [buf][b][i][t] bf16
#define OFF_HTI  (OFF_HIT + HSZ)             // h [buf][b][t][i] bf16
#define OFF_DOB  (OFF_HTI + HSZ)             // do [b][t][d] bf16
#define OFF_DOT  (OFF_DOB + DOSZ/2)          // (unused, layout spacing)
// aliases (temporally disjoint):
//   xbf (bf16 x, pre-loop)        -> OFF_ORET lower half
//   qbf (bf16 q, from p1b)        -> OFF_ORET upper half (until r2 writes oret)
//   wbf (bf16 wk/wv/wq, pre-loop) -> OFF_KBFf region (p1b overwrites after p1a)
//   hqb (bf16 hq, post-loop)      -> OFF_K region (k f32 dead after loop)

typedef __attribute__((ext_vector_type(8))) short s8v;    // 8 bf16 in 4 VGPR
typedef __attribute__((ext_vector_type(4))) float f4v;    // mfma C/D

__device__ __forceinline__ float bf2f(__hip_bfloat16 v){ return __bfloat162float(v); }
__device__ __forceinline__ float bfu2f(unsigned short u){ return __uint_as_float(((unsigned)u)<<16); }
__device__ __forceinline__ unsigned short f2bfu(float f){
  unsigned x = __float_as_uint(f);
  return (unsigned short)((x + 0x7FFFu + ((x>>16)&1u)) >> 16);
}
__device__ __forceinline__ float4 u42f4(ushort4 u){
  float4 r; r.x=bfu2f(u.x); r.y=bfu2f(u.y); r.z=bfu2f(u.z); r.w=bfu2f(u.w); return r;
}
__device__ __forceinline__ ushort4 f42u4(float4 v){
  ushort4 r; r.x=f2bfu(v.x); r.y=f2bfu(v.y); r.z=f2bfu(v.z); r.w=f2bfu(v.w); return r;
}
__device__ __forceinline__ float ldin(const void* p, size_t i, int f){
  return f ? ((const float*)p)[i] : bf2f(((const __hip_bfloat16*)p)[i]);
}
__device__ __forceinline__ float4 ld4g(const void* p, size_t i, int f){
  if(f) return ((const float4*)p)[i>>2];
  return u42f4(((const ushort4*)p)[i>>2]);
}
__device__ __forceinline__ void unp8(uint4 u, float* f){
  f[0]=bfu2f((unsigned short)(u.x&0xffffu)); f[1]=bfu2f((unsigned short)(u.x>>16));
  f[2]=bfu2f((unsigned short)(u.y&0xffffu)); f[3]=bfu2f((unsigned short)(u.y>>16));
  f[4]=bfu2f((unsigned short)(u.z&0xffffu)); f[5]=bfu2f((unsigned short)(u.z>>16));
  f[6]=bfu2f((unsigned short)(u.w&0xffffu)); f[7]=bfu2f((unsigned short)(u.w>>16));
}
__device__ __forceinline__ uint4 pck8(const float* f){
  uint4 u;
  u.x = (unsigned)f2bfu(f[0]) | ((unsigned)f2bfu(f[1])<<16);
  u.y = (unsigned)f2bfu(f[2]) | ((unsigned)f2bfu(f[3])<<16);
  u.z = (unsigned)f2bfu(f[4]) | ((unsigned)f2bfu(f[5])<<16);
  u.w = (unsigned)f2bfu(f[6]) | ((unsigned)f2bfu(f[7])<<16);
  return u;
}

__device__ __forceinline__ float blockReduceSum(float v, float* sm){
  #pragma unroll
  for(int o=32;o>0;o>>=1) v += __shfl_down(v,o,64);
  int wid = threadIdx.x>>6, lane = threadIdx.x&63;
  __syncthreads();
  if(lane==0) sm[wid]=v;
  __syncthreads();
  return sm[0]+sm[1]+sm[2]+sm[3];
}

__device__ __forceinline__ float2 blockReduceSum2(float a, float b, float* sm){
  #pragma unroll
  for(int o=32;o>0;o>>=1){ a += __shfl_down(a,o,64); b += __shfl_down(b,o,64); }
  int wid = threadIdx.x>>6, lane = threadIdx.x&63;
  __syncthreads();
  if(lane==0){ sm[wid]=a; sm[4+wid]=b; }
  __syncthreads();
  float2 r; r.x = sm[0]+sm[1]+sm[2]+sm[3]; r.y = sm[4]+sm[5]+sm[6]+sm[7];
  return r;
}

// ---------------- D0: runtime input-dtype detection ----------------
__global__ void d0_detect(const void* __restrict__ x, float* __restrict__ ws){
  __shared__ int cnt;
  if(threadIdx.x==0) cnt=0;
  __syncthreads();
  unsigned w = ((const unsigned*)x)[(size_t)threadIdx.x*931 + 17];
  int e = (w>>7)&0xFF;
  if(e>=110 && e<=140) atomicAdd(&cnt,1);
  __syncthreads();
  if(threadIdx.x==0) ((int*)(ws+OFF_FLAG))[0] = (cnt<32) ? 1 : 0;  // 1 => f32 inputs
}

// ---------------- P0: init states / slabs / ticks + cvt x,wk/wv/wq -> bf16 ----------------
__global__ void p0_init(float* __restrict__ ws, const void* __restrict__ w1,
                        const void* __restrict__ w2, const void* __restrict__ ln,
                        const void* __restrict__ x, const void* __restrict__ wk,
                        const void* __restrict__ wv, const void* __restrict__ wq){
  int f = ((const int*)(ws+OFF_FLAG))[0];
  unsigned short* bst = (unsigned short*)(ws + OFF_BST);
  size_t id = (size_t)blockIdx.x*blockDim.x + threadIdx.x;
  size_t stride = (size_t)gridDim.x*blockDim.x;
  ushort4 z4 = {0,0,0,0};
  for(size_t t4=id; t4<(size_t)(STSZ/4); t4+=stride){
    size_t e4 = t4 % (size_t)(I_*D_/4);
    *(ushort4*)(bst + (size_t)STSZ + t4*4)   = f42u4(ld4g(w1, e4*4, f));  // BMW1
    *(ushort4*)(bst + (size_t)3*STSZ + t4*4) = f42u4(ld4g(w2, e4*4, f));  // BMW2
    *(ushort4*)(bst + t4*4) = z4;                                          // BSW1
    *(ushort4*)(bst + (size_t)2*STSZ + t4*4) = z4;                         // BSW2
  }
  unsigned short* xbf = (unsigned short*)(ws + OFF_ORET);
  unsigned short* wbf = (unsigned short*)(ws + OFF_KBFf);
  for(size_t t4=id; t4<(size_t)(KBUF/4); t4+=stride)
    *(ushort4*)(xbf + t4*4) = f42u4(ld4g(x, t4*4, f));
  for(size_t t4=id; t4<(size_t)(3*D_*D_/4); t4+=stride){
    int pid = (int)(t4 / (D_*D_/4));
    size_t e4 = t4 % (size_t)(D_*D_/4);
    const void* W = (pid==0)?wk:((pid==1)?wv:wq);
    *(ushort4*)(wbf + t4*4) = f42u4(ld4g(W, e4*4, f));
  }
  for(size_t t=id; t<(size_t)(B_*D_); t+=stride){
    ws[OFF_MLN+t] = ldin(ln,t % D_,f);
    ws[OFF_SLN+t] = 0.f;
  }
  for(size_t t=id; t<(size_t)(NC_*B_*SLABSTR); t+=stride) ws[OFF_SLAB+t]=0.f;
  int* tick = (int*)(ws + OFF_TICK);
  for(size_t t=id; t<192; t+=stride) tick[t]=0;
}

// ---------------- P1a (MFMA): k,v,q = silu(x@W^T) ----------------
// grid dim3(32,8,3): blockIdx.x spans ALL B*S = 2048 rows / 64
__global__ void __launch_bounds__(256) p1a(float* __restrict__ ws){
  const unsigned short* xbf = (const unsigned short*)(ws + OFF_ORET);
  const unsigned short* wbf = (const unsigned short*)(ws + OFF_KBFf);
  int pid = blockIdx.z;
  float* outp = ws + ((pid==0)?OFF_K:((pid==1)?OFF_V:OFF_Q));
  const unsigned short* W = wbf + (size_t)pid*D_*D_;
  int r0 = blockIdx.x*64, j0 = blockIdx.y*64;
  int w = threadIdx.x>>6, lane = threadIdx.x&63;
  int col = lane&15, lg = lane>>4;
  f4v acc[4] = {{0,0,0,0},{0,0,0,0},{0,0,0,0},{0,0,0,0}};
  for(int k0=0;k0<512;k0+=32){
    s8v bB = __builtin_bit_cast(s8v, *(const uint4*)(W + (size_t)(j0 + w*16 + col)*512 + k0 + lg*8));
    #pragma unroll
    for(int rg=0;rg<4;rg++){
      s8v aA = __builtin_bit_cast(s8v, *(const uint4*)(xbf + (size_t)(r0 + rg*16 + col)*512 + k0 + lg*8));
      acc[rg] = __builtin_amdgcn_mfma_f32_16x16x32_bf16(aA, bB, acc[rg], 0,0,0);
    }
  }
  #pragma unroll
  for(int rg=0;rg<4;rg++)
    #pragma unroll
    for(int j=0;j<4;j++){
      float z = acc[rg][j];
      outp[(size_t)(r0 + rg*16 + lg*4 + j)*512 + j0 + w*16 + col] = z/(1.f+expf(-z));
    }
}

// ---------------- P1b: rms(k)(+bf16 k),rms(q)(+bf16 q), |k|^2, gates ----------------
__global__ void __launch_bounds__(256) p1b(const void* __restrict__ x,
                    const void* __restrict__ kn,
                    const void* __restrict__ qn,
                    const void* __restrict__ aw,
                    const void* __restrict__ tw,
                    const void* __restrict__ ew,
                    float* __restrict__ ws){
  int f = ((const int*)(ws+OFF_FLAG))[0];
  int tok = blockIdx.x; int tid = threadIdx.x;
  __shared__ float sm[8];
  float* krow = ws + OFF_K + (size_t)tok*512;
  float* qrow = ws + OFF_Q + (size_t)tok*512;
  float a = krow[tid], b = krow[tid+256];
  float ss = blockReduceSum(a*a+b*b, sm);
  float n = rsqrtf(ss*(1.f/512.f) + 1e-6f);
  float k1v = a*n*ldin(kn,tid,f);
  float k2v = b*n*ldin(kn,tid+256,f);
  krow[tid]=k1v; krow[tid+256]=k2v;
  unsigned short* kbf = (unsigned short*)(ws + OFF_KBFf);
  kbf[(size_t)tok*512+tid]     = f2bfu(k1v);
  kbf[(size_t)tok*512+tid+256] = f2bfu(k2v);
  float kn2 = blockReduceSum(k1v*k1v+k2v*k2v, sm);
  if(tid==0) ws[OFF_KN2+tok]=kn2;
  a = qrow[tid]; b = qrow[tid+256];
  ss = blockReduceSum(a*a+b*b, sm);
  n = rsqrtf(ss*(1.f/512.f)+1e-6f);
  float q1 = a*n*ldin(qn,tid,f);
  float q2 = b*n*ldin(qn,tid+256,f);
  qrow[tid]=q1; qrow[tid+256]=q2;
  unsigned short* qbf = (unsigned short*)(ws + OFF_ORET + KBUF/2);
  qbf[(size_t)tok*512+tid]     = f2bfu(q1);
  qbf[(size_t)tok*512+tid+256] = f2bfu(q2);
  float x1=ldin(x,(size_t)tok*512+tid,f), x2=ldin(x,(size_t)tok*512+tid+256,f);
  float td = blockReduceSum(x1*ldin(tw,tid,f) + x2*ldin(tw,tid+256,f), sm);
  float ad = blockReduceSum(x1*ldin(aw,tid,f) + x2*ldin(aw,tid+256,f), sm);
  float ed = blockReduceSum(x1*ldin(ew,tid,f) + x2*ldin(ew,tid+256,f), sm);
  if(tid==0){
    ws[OFF_TH+tok] = 0.01f/(1.f+expf(-td));
    ws[OFF_AL+tok] = 1.f/(1.f+expf(-ad));
    ws[OFF_ET+tok] = 1.f/(1.f+expf(-ed));
  }
}

// ---------------- TRK: kbt = transpose(kbf) ----------------
__global__ void __launch_bounds__(256) tr_k(float* __restrict__ ws){
  const unsigned short* kbf = (const unsigned short*)(ws + OFF_KBFf);
  unsigned short* kbt = (unsigned short*)(ws + OFF_KBTf);
  int b = blockIdx.z, st = blockIdx.y, dt = blockIdx.x;
  int s0 = st*64, d0 = dt*64;
  __shared__ unsigned short t[64][72];
  int tid = threadIdx.x;
  #pragma unroll
  for(int q=0;q<4;q++){
    int idx = tid + q*256; int r = idx>>4, cq = idx&15;
    ushort4 u = *(const ushort4*)(kbf + ((size_t)(b*512 + s0 + r))*512 + d0 + cq*4);
    *(ushort4*)&t[r][cq*4] = u;
  }
  __syncthreads();
  #pragma unroll
  for(int q=0;q<4;q++){
    int idx = tid + q*256; int d = idx>>4, sq = idx&15;
    ushort4 u; u.x=t[sq*4+0][d]; u.y=t[sq*4+1][d]; u.z=t[sq*4+2][d]; u.w=t[sq*4+3][d];
    *(ushort4*)(kbt + ((size_t)(b*512 + d0 + d))*512 + s0 + sq*4) = u;
  }
}

// ---------------- K1 (MFMA): update W1(+ln) w/ chunk c-1 grads; z,h for chunk c ----------------
__global__ void __launch_bounds__(256) k1_w1(float* __restrict__ ws, int c){
  unsigned short* bsw1 = (unsigned short*)(ws + OFF_BST);
  unsigned short* bmw1 = bsw1 + STSZ;
  const unsigned short* kbf = (const unsigned short*)(ws + OFF_KBFf);
  const unsigned short* kbt = (const unsigned short*)(ws + OFF_KBTf);
  int b = blockIdx.y, bx = blockIdx.x, tid = threadIdx.x;
  __shared__ float sE[32], sC[32], scal[3];
  if(c>0){
    const float* slab = ws + OFF_SLAB + ((long)(c-1)*B_ + b)*SLABSTR;
    if(tid<32){ sE[tid]=slab[128+tid]; sC[tid]=slab[160+tid]; }
    if(tid>=32 && tid<35) scal[tid-32]=slab[192+(tid-32)];
  }
  __syncthreads();
  float PE = c>0? scal[0]:1.f, PB = c>0? scal[1]:1.f, Q = c>0? scal[2]:0.f;
  if(bx==64){
    if(c>0){
      for(int d=tid; d<512; d+=256){
        float gE=0,gC=0;
        for(int u=0;u<32;u++){
          float dl = ws[OFF_DLN + ((size_t)(b*32+u))*512 + d];
          gE += sE[u]*dl; gC += sC[u]*dl;
        }
        size_t ix = OFF_SLN + (size_t)b*512 + d;
        float sv=ws[ix], mv=ws[ix + (OFF_MLN-OFF_SLN)];
        ws[ix] = PE*sv - gE;
        ws[ix + (OFF_MLN-OFF_SLN)] = PB*mv + Q*sv - gC;
      }
    }
    return;
  }
  __shared__ __align__(16) float gbf[4][2][16][36];
  __shared__ __align__(16) unsigned short ztile[4][16][40];
  __shared__ __align__(16) float zred[4][16][32];
  __shared__ float hredL[32];
  int w = tid>>6, lane = tid&63;
  int i0 = bx*16;
  int col = lane&15, lg = lane>>4;
  int rr = lane>>2, c0 = (lane&3)*8;
  s8v aE = {}, aC = {};
  if(c>0){
    const float* dp = ws + OFF_DHP + ((size_t)(b*I_ + i0 + col))*32 + lg*8;
    float4 dv0 = *(const float4*)dp;
    float4 dv1 = *(const float4*)(dp+4);
    float dv[8] = {dv0.x,dv0.y,dv0.z,dv0.w,dv1.x,dv1.y,dv1.z,dv1.w};
    #pragma unroll
    for(int j=0;j<8;j++){
      aE[j] = (short)f2bfu(sE[lg*8+j]*dv[j]);
      aC[j] = (short)f2bfu(sC[lg*8+j]*dv[j]);
    }
  }
  f4v zacc0 = {0.f,0.f,0.f,0.f}, zacc1 = {0.f,0.f,0.f,0.f};
  const int d0w = w*128;
  const size_t srowbase = ((size_t)(b*I_ + i0))*512;
  const size_t kprow = (size_t)(c-1)*32;
  for(int sl=0; sl<4; sl++){
    int dbase = d0w + sl*32;
    size_t gaddr = srowbase + (size_t)rr*512 + dbase + c0;
    if(c>0){
      #pragma unroll
      for(int t2=0;t2<2;t2++){
        int dt = dbase + t2*16;
        const unsigned short* kp = kbt + ((size_t)(b*512 + dt + col))*512 + kprow + lg*8;
        s8v kB = __builtin_bit_cast(s8v, *(const uint4*)kp);
        f4v zero4 = {0.f,0.f,0.f,0.f};
        f4v gE4 = __builtin_amdgcn_mfma_f32_16x16x32_bf16(aE, kB, zero4, 0,0,0);
        f4v gC4 = __builtin_amdgcn_mfma_f32_16x16x32_bf16(aC, kB, zero4, 0,0,0);
        #pragma unroll
        for(int j=0;j<4;j++){
          gbf[w][0][lg*4+j][t2*16+col] = gE4[j];
          gbf[w][1][lg*4+j][t2*16+col] = gC4[j];
        }
      }
      uint4 su = *(uint4*)(bsw1 + gaddr);
      uint4 mu = *(uint4*)(bmw1 + gaddr);
      float s8[8], m8[8];
      unp8(su, s8); unp8(mu, m8);
      float ns[8], nmv[8];
      #pragma unroll
      for(int j=0;j<8;j++){
        float ge = gbf[w][0][rr][c0+j];
        float gc = gbf[w][1][rr][c0+j];
        ns[j]  = PE*s8[j] - ge;
        nmv[j] = PB*m8[j] + Q*s8[j] - gc;
      }
      *(uint4*)(bsw1 + gaddr) = pck8(ns);
      uint4 nmu = pck8(nmv);
      *(uint4*)(bmw1 + gaddr) = nmu;
      *(uint4*)&ztile[w][rr][c0] = nmu;
    } else {
      uint4 mu = *(uint4*)(bmw1 + gaddr);
      *(uint4*)&ztile[w][rr][c0] = mu;
    }
    if(c<16){
      s8v mA = __builtin_bit_cast(s8v, *(const uint4*)&ztile[w][col][lg*8]);
      const unsigned short* kc0 = kbf + ((size_t)(b*512 + c*32 + col))*512 + dbase + lg*8;
      s8v kB0 = __builtin_bit_cast(s8v, *(const uint4*)kc0);
      s8v kB1 = __builtin_bit_cast(s8v, *(const uint4*)(kc0 + (size_t)16*512));
      zacc0 = __builtin_amdgcn_mfma_f32_16x16x32_bf16(mA, kB0, zacc0, 0,0,0);
      zacc1 = __builtin_amdgcn_mfma_f32_16x16x32_bf16(mA, kB1, zacc1, 0,0,0);
    }
  }
  if(c<16){
    #pragma unroll
    for(int j=0;j<4;j++){
      zred[w][lg*4+j][col]    = zacc0[j];
      zred[w][lg*4+j][16+col] = zacc1[j];
    }
    if(tid<32) hredL[tid]=0.f;
    __syncthreads();
    unsigned short* hit = (unsigned short*)(ws + OFF_HIT) + (size_t)(c&1)*HSZ;
    unsigned short* hti = (unsigned short*)(ws + OFF_HTI) + (size_t)(c&1)*HSZ;
    #pragma unroll
    for(int e=0;e<2;e++){
      int idx = tid*2+e; int row = idx>>5, t = idx&31;
      float z = zred[0][row][t]+zred[1][row][t]+zred[2][row][t]+zred[3][row][t];
      size_t zb = ((size_t)(b*I_ + i0 + row))*32 + t;
      ws[OFF_Z1+zb] = z;
      float h = z/(1.f+expf(-z));
      unsigned short hb = f2bfu(h);
      hit[zb] = hb;
      hti[((size_t)(b*C_+t))*I_ + i0 + row] = hb;
      atomicAdd(&hredL[t], h*h);
    }
    __syncthreads();
    if(tid<32) atomicAdd(ws + OFF_SLAB + ((size_t)c*B_ + b)*SLABSTR + tid, hredL[tid]);
  }
}

// ---------------- K2 (MFMA): update W2 w/ chunk c-1 grads; o = M2@h_c ----------------
__global__ void __launch_bounds__(256) k2_w2(float* __restrict__ ws, int c){
  unsigned short* bsw2 = (unsigned short*)(ws + OFF_BST) + (size_t)2*STSZ;
  unsigned short* bmw2 = bsw2 + STSZ;
  const unsigned short* hitp = (const unsigned short*)(ws + OFF_HIT) + (size_t)((c-1)&1)*HSZ;
  const unsigned short* htic = (const unsigned short*)(ws + OFF_HTI) + (size_t)(c&1)*HSZ;
  const unsigned short* dob = (const unsigned short*)(ws + OFF_DOB);
  int b = blockIdx.y, bx = blockIdx.x, tid = threadIdx.x;
  int d0 = bx*16;
  __shared__ float sE[32], sC[32], scal[3];
  __shared__ float doT[16][33];
  __shared__ __align__(16) float gbf[4][2][16][36];
  __shared__ __align__(16) unsigned short ztile[4][16][40];
  __shared__ __align__(16) float ored[4][16][32];
  if(c>0){
    const float* slab = ws + OFF_SLAB + ((long)(c-1)*B_+b)*SLABSTR;
    if(tid<32){ sE[tid]=slab[128+tid]; sC[tid]=slab[160+tid]; }
    if(tid>=32&&tid<35) scal[tid-32]=slab[192+tid-32];
    // stage do^T tile: doT[d-local][t] from dob [t][d] (coalesced 32B reads)
    #pragma unroll
    for(int e=0;e<2;e++){
      int idx = tid + e*256; int tt = idx>>4, dl = idx&15;
      doT[dl][tt] = bfu2f(dob[((size_t)(b*C_+tt))*512 + d0 + dl]);
    }
  }
  __syncthreads();
  float PE = c>0?scal[0]:1.f, PB=c>0?scal[1]:1.f, Q=c>0?scal[2]:0.f;
  int w = tid>>6, lane = tid&63;
  int col = lane&15, lg = lane>>4;
  int rr = lane>>2, c0 = (lane&3)*8;
  s8v aE = {}, aC = {};
  if(c>0){
    #pragma unroll
    for(int j=0;j<8;j++){
      float dvj = doT[col][lg*8+j];
      aE[j] = (short)f2bfu(sE[lg*8+j]*dvj);
      aC[j] = (short)f2bfu(sC[lg*8+j]*dvj);
    }
  }
  f4v oacc0 = {0.f,0.f,0.f,0.f}, oacc1 = {0.f,0.f,0.f,0.f};
  const size_t srowbase = ((size_t)(b*D_ + d0))*1024;
  size_t ga0 = srowbase + (size_t)rr*1024 + w*256 + c0;
  uint4 su={0,0,0,0}, mu, svn=su, mvn;
  if(c>0) su = *(uint4*)(bsw2 + ga0);
  mu = *(uint4*)(bmw2 + ga0);
  for(int sl=0; sl<8; sl++){
    int ibase = w*256 + sl*32;
    size_t gaddr = srowbase + (size_t)rr*1024 + ibase + c0;
    if(sl<7){
      if(c>0) svn = *(uint4*)(bsw2 + gaddr + 32);
      mvn = *(uint4*)(bmw2 + gaddr + 32);
    }
    if(c>0){
      #pragma unroll
      for(int t2=0;t2<2;t2++){
        const unsigned short* hp = hitp + ((size_t)(b*I_ + ibase + t2*16 + col))*32 + lg*8;
        s8v hB = __builtin_bit_cast(s8v, *(const uint4*)hp);
        f4v zero4 = {0.f,0.f,0.f,0.f};
        f4v gE4 = __builtin_amdgcn_mfma_f32_16x16x32_bf16(aE, hB, zero4, 0,0,0);
        f4v gC4 = __builtin_amdgcn_mfma_f32_16x16x32_bf16(aC, hB, zero4, 0,0,0);
        #pragma unroll
        for(int j=0;j<4;j++){
          gbf[w][0][lg*4+j][t2*16+col] = gE4[j];
          gbf[w][1][lg*4+j][t2*16+col] = gC4[j];
        }
      }
      float s8[8], m8[8];
      unp8(su, s8); unp8(mu, m8);
      float ns[8], nmv[8];
      #pragma unroll
      for(int j=0;j<8;j++){
        ns[j]  = PE*s8[j] - gbf[w][0][rr][c0+j];
        nmv[j] = PB*m8[j] + Q*s8[j] - gbf[w][1][rr][c0+j];
      }
      *(uint4*)(bsw2 + gaddr) = pck8(ns);
      uint4 nmu = pck8(nmv);
      *(uint4*)(bmw2 + gaddr) = nmu;
      *(uint4*)&ztile[w][rr][c0] = nmu;
    } else {
      *(uint4*)&ztile[w][rr][c0] = mu;
    }
    if(c<16){
      s8v mA = __builtin_bit_cast(s8v, *(const uint4*)&ztile[w][col][lg*8]);
      const unsigned short* hb = htic + ((size_t)(b*C_+col))*I_ + ibase + lg*8;
      s8v hB0 = __builtin_bit_cast(s8v, *(const uint4*)hb);
      s8v hB1 = __builtin_bit_cast(s8v, *(const uint4*)(hb + (size_t)16*I_));
      oacc0 = __builtin_amdgcn_mfma_f32_16x16x32_bf16(mA, hB0, oacc0, 0,0,0);
      oacc1 = __builtin_amdgcn_mfma_f32_16x16x32_bf16(mA, hB1, oacc1, 0,0,0);
    }
    su = svn; mu = mvn;
  }
  if(c<16){
    #pragma unroll
    for(int j=0;j<4;j++){
      ored[w][lg*4+j][col]    = oacc0[j];
      ored[w][lg*4+j][16+col] = oacc1[j];
    }
    __syncthreads();
    #pragma unroll
    for(int e=0;e<2;e++){
      int idx = tid*2+e; int row = idx>>5, t = idx&31;
      float o = ored[0][row][t]+ored[1][row][t]+ored[2][row][t]+ored[3][row][t];
      ws[OFF_OB + ((size_t)(b*C_+t))*512 + d0 + row] = o;
    }
  }
}

// ---------------- K3: per-token rms backward ----------------
__global__ void __launch_bounds__(256) k3_rms(float* __restrict__ ws, int c){
  int t = blockIdx.x, b = blockIdx.y, tid=threadIdx.x;
  __shared__ float sm[8];
  int tok = b*S_ + c*32 + t;
  const float* orow = ws + OFF_OB + ((size_t)(b*32+t))*512;
  const float* krow = ws + OFF_K + (size_t)tok*512;
  const float* vrow = ws + OFF_V + (size_t)tok*512;
  const float* lrow = ws + OFF_MLN + (size_t)b*512;
  float th = ws[OFF_TH + tok];
  float o1=orow[tid], o2=orow[tid+256];
  float mu = blockReduceSum(o1*o1+o2*o2, sm)*(1.f/512.f);
  float n = rsqrtf(mu + 1e-6f);
  float l1=lrow[tid], l2=lrow[tid+256];
  float k1=krow[tid], k2=krow[tid+256];
  float v1=vrow[tid], v2=vrow[tid+256];
  float c2 = 2.f*th*(1.f/512.f);
  float u1 = c2*(k1 + o1*n*l1 - v1);
  float u2 = c2*(k2 + o2*n*l2 - v2);
  float s1 = blockReduceSum(u1*l1*o1 + u2*l2*o2, sm);
  float dln1 = u1*o1*n, dln2v = u2*o2*n;
  float f = n*n*n*s1*(1.f/512.f);
  float do1 = n*l1*u1 - f*o1;
  float do2 = n*l2*u2 - f*o2;
  float2 dd = blockReduceSum2(do1*do1+do2*do2, dln1*dln1+dln2v*dln2v, sm);
  float* dlrow = ws + OFF_DLN + ((size_t)(b*32+t))*512;
  dlrow[tid]=dln1; dlrow[tid+256]=dln2v;
  unsigned short* dob = (unsigned short*)(ws + OFF_DOB);
  dob[((size_t)(b*C_+t))*512 + tid]       = f2bfu(do1);
  dob[((size_t)(b*C_+t))*512 + tid + 256] = f2bfu(do2);
  if(tid==0){
    float* slab = ws + OFF_SLAB + ((size_t)c*B_+b)*SLABSTR;
    slab[64+t]=dd.x; slab[96+t]=dd.y;
  }
}

// ---------------- K4 (MFMA): dh = M2^T do, dhp, grad-norm + scan scalars ----------------
__global__ void __launch_bounds__(256) k4_dh(float* __restrict__ ws, int c){
  unsigned short* bmw2 = (unsigned short*)(ws + OFF_BST) + (size_t)3*STSZ;
  const unsigned short* dob = (const unsigned short*)(ws + OFF_DOB);
  int bx = blockIdx.x, b = blockIdx.y, tid = threadIdx.x;
  int i0 = bx*16;
  __shared__ __align__(16) unsigned short m2u[16][520];
  __shared__ __align__(16) float dred[4][16][32];
  __shared__ float red[32], coefl[32], bsufl[32];
  __shared__ int lastf;
  #pragma unroll
  for(int q=0;q<4;q++){
    int idx = tid + q*256; int d = idx>>1, half = idx&1;
    uint4 v = *(const uint4*)(bmw2 + ((size_t)(b*D_+d))*1024 + i0 + half*8);
    unsigned short tmp[8]; *(uint4*)tmp = v;
    #pragma unroll
    for(int jj=0;jj<8;jj++) m2u[half*8+jj][d] = tmp[jj];
  }
  if(tid<32) red[tid]=0.f;
  __syncthreads();
  int w = tid>>6, lane = tid&63;
  int col = lane&15, lg = lane>>4;
  f4v acc0 = {0.f,0.f,0.f,0.f}, acc1 = {0.f,0.f,0.f,0.f};
  #pragma unroll
  for(int ks=0;ks<4;ks++){
    int k0 = w*128 + ks*32;
    s8v mA = __builtin_bit_cast(s8v, *(const uint4*)&m2u[col][k0 + lg*8]);
    const unsigned short* dp = dob + ((size_t)(b*C_+col))*512 + k0 + lg*8;
    s8v dB0 = __builtin_bit_cast(s8v, *(const uint4*)dp);
    s8v dB1 = __builtin_bit_cast(s8v, *(const uint4*)(dp + (size_t)16*512));
    acc0 = __builtin_amdgcn_mfma_f32_16x16x32_bf16(mA, dB0, acc0, 0,0,0);
    acc1 = __builtin_amdgcn_mfma_f32_16x16x32_bf16(mA, dB1, acc1, 0,0,0);
  }
  #pragma unroll
  for(int j=0;j<4;j++){
    dred[w][lg*4+j][col]    = acc0[j];
    dred[w][lg*4+j][16+col] = acc1[j];
  }
  __syncthreads();
  #pragma unroll
  for(int e=0;e<2;e++){
    int idx = tid*2+e; int row = idx>>5, t = idx&31;
    float dh = dred[0][row][t]+dred[1][row][t]+dred[2][row][t]+dred[3][row][t];
    size_t zb = ((size_t)(b*I_ + i0 + row))*32 + t;
    float z = ws[OFF_Z1+zb];
    float s = 1.f/(1.f+expf(-z));
    float dp_ = dh * s*(1.f + z*(1.f-s));
    ws[OFF_DHP+zb] = dp_;
    atomicAdd(&red[t], dp_*dp_);
  }
  __syncthreads();
  float* slab = ws + OFF_SLAB + ((size_t)c*B_+b)*SLABSTR;
  if(tid<32) atomicAdd(&slab[32+tid], red[tid]);
  __threadfence();
  __syncthreads();
  if(tid==0){
    int* tick = (int*)(ws+OFF_TICK);
    lastf = (atomicAdd(&tick[c*B_+b],1) == 63) ? 1 : 0;
  }
  __syncthreads();
  if(!lastf) return;
  if(tid<32){
    float sqd = atomicAdd(&slab[32+tid], 0.f);
    float hn  = atomicAdd(&slab[0+tid], 0.f);
    float don2 = slab[64+tid], dl2 = slab[96+tid];
    float kn2 = ws[OFF_KN2 + b*S_ + c*32 + tid];
    float sq = sqd*kn2 + don2*hn + dl2;
    coefl[tid] = fminf(1.f/(sqrtf(sq)+1e-6f), 1.f);
  }
  __syncthreads();
  if(tid==0){
    const float* eta = ws + OFF_ET + b*S_ + c*32;
    const float* alp = ws + OFF_AL + b*S_ + c*32;
    float Esuf=1.f, Bsuf=1.f, cu=1.f;
    for(int u=31;u>=0;u--){
      if(u<31){
        float e1 = eta[u+1], b1 = 1.f-alp[u+1];
        Esuf *= e1; Bsuf *= b1;
        cu = Bsuf + e1*cu;
      }
      bsufl[u]=Bsuf;
      slab[128+u] = Esuf*coefl[u];
      slab[160+u] = cu*coefl[u];
    }
    float PE = Esuf*eta[0];
    float PB = Bsuf*(1.f-alp[0]);
    float Q=0.f, Epre=1.f;
    for(int t2=0;t2<32;t2++){ Epre *= eta[t2]; Q += bsufl[t2]*Epre; }
    slab[192]=PE; slab[193]=PB; slab[194]=Q;
  }
}

// ---------------- R1 (MFMA): hq = silu(q @ M1^T), bf16 out ----------------
__global__ void __launch_bounds__(256) r1_gemm(float* __restrict__ ws){
  const unsigned short* qbf = (const unsigned short*)(ws + OFF_ORET + KBUF/2);
  const unsigned short* bmw1 = (const unsigned short*)(ws + OFF_BST) + STSZ;
  unsigned short* hqb = (unsigned short*)(ws + OFF_K);
  int b = blockIdx.z;
  int s0 = blockIdx.x*64, i0 = blockIdx.y*64;
  int w = threadIdx.x>>6, lane = threadIdx.x&63;
  int col = lane&15, lg = lane>>4;
  const unsigned short* qb = qbf + (size_t)b*S_*D_;
  const unsigned short* w1b = bmw1 + (size_t)b*I_*D_;
  f4v acc[4] = {{0,0,0,0},{0,0,0,0},{0,0,0,0},{0,0,0,0}};
  for(int k0=0;k0<512;k0+=32){
    s8v bB = __builtin_bit_cast(s8v, *(const uint4*)(w1b + (size_t)(i0 + w*16 + col)*512 + k0 + lg*8));
    #pragma unroll
    for(int rg=0;rg<4;rg++){
      s8v aA = __builtin_bit_cast(s8v, *(const uint4*)(qb + (size_t)(s0 + rg*16 + col)*512 + k0 + lg*8));
      acc[rg] = __builtin_amdgcn_mfma_f32_16x16x32_bf16(aA, bB, acc[rg], 0,0,0);
    }
  }
  unsigned short* hb = hqb + (size_t)b*S_*I_;
  #pragma unroll
  for(int rg=0;rg<4;rg++)
    #pragma unroll
    for(int j=0;j<4;j++){
      float z = acc[rg][j];
      hb[(size_t)(s0 + rg*16 + lg*4 + j)*1024 + i0 + w*16 + col] = f2bfu(z/(1.f+expf(-z)));
    }
}

// ---------------- R2 (MFMA): oret = hq @ M2^T ----------------
__global__ void __launch_bounds__(256) r2_gemm(float* __restrict__ ws){
  const unsigned short* hqb = (const unsigned short*)(ws + OFF_K);
  const unsigned short* bmw2 = (const unsigned short*)(ws + OFF_BST) + (size_t)3*STSZ;
  int b=blockIdx.z;
  int s0=blockIdx.x*64, d0=blockIdx.y*64;
  int w = threadIdx.x>>6, lane = threadIdx.x&63;
  int col = lane&15, lg = lane>>4;
  const unsigned short* hb = hqb + (size_t)b*S_*I_;
  const unsigned short* w2b = bmw2 + (size_t)b*D_*I_;
  f4v acc[4] = {{0,0,0,0},{0,0,0,0},{0,0,0,0},{0,0,0,0}};
  for(int k0=0;k0<1024;k0+=32){
    s8v bB = __builtin_bit_cast(s8v, *(const uint4*)(w2b + (size_t)(d0 + w*16 + col)*1024 + k0 + lg*8));
    #pragma unroll
    for(int rg=0;rg<4;rg++){
      s8v aA = __builtin_bit_cast(s8v, *(const uint4*)(hb + (size_t)(s0 + rg*16 + col)*1024 + k0 + lg*8));
      acc[rg] = __builtin_amdgcn_mfma_f32_16x16x32_bf16(aA, bB, acc[rg], 0,0,0);
    }
  }
  float* od = ws + OFF_ORET + (size_t)b*S_*D_;
  #pragma unroll
  for(int rg=0;rg<4;rg++)
    #pragma unroll
    for(int j=0;j<4;j++)
      od[(size_t)(s0 + rg*16 + lg*4 + j)*512 + d0 + w*16 + col] = acc[rg][j];
}

// ---------------- R3: out = q + rms(oret, Mln) ----------------
__global__ void __launch_bounds__(256) r3_out(float* __restrict__ ws, void* __restrict__ out){
  int f = ((const int*)(ws+OFF_FLAG))[0];
  int tok=blockIdx.x, tid=threadIdx.x;
  int b = tok >> 9;
  __shared__ float sm[8];
  const float* orow = ws + OFF_ORET + (size_t)tok*512;
  const float* qrow = ws + OFF_Q + (size_t)tok*512;
  const float* lrow = ws + OFF_MLN + (size_t)b*512;
  float o1=orow[tid], o2=orow[tid+256];
  float mu = blockReduceSum(o1*o1+o2*o2, sm)*(1.f/512.f);
  float n = rsqrtf(mu+1e-6f);
  float r1v = qrow[tid]     + o1*n*lrow[tid];
  float r2v = qrow[tid+256] + o2*n*lrow[tid+256];
  if(f){
    ((float*)out)[(size_t)tok*512+tid]     = r1v;
    ((float*)out)[(size_t)tok*512+tid+256] = r2v;
  } else {
    ((__hip_bfloat16*)out)[(size_t)tok*512+tid]     = __float2bfloat16(r1v);
    ((__hip_bfloat16*)out)[(size_t)tok*512+tid+256] = __float2bfloat16(r2v);
  }
}

extern "C" void kernel_launch(void* const* d_in, const int* in_sizes, int n_in,
                              void* d_out, int out_size, void* d_ws, size_t ws_size,
                              hipStream_t stream) {
  const void* x  = d_in[0];
  const void* wq = d_in[1];
  const void* wk = d_in[2];
  const void* wv = d_in[3];
  const void* qn = d_in[4];
  const void* kn = d_in[5];
  const void* aw = d_in[6];
  const void* tw = d_in[7];
  const void* ew = d_in[8];
  const void* w1 = d_in[9];
  const void* w2 = d_in[10];
  const void* ln = d_in[11];
  float* ws = (float*)d_ws;

  d0_detect<<<1,64,0,stream>>>(x, ws);
  p0_init<<<2048,256,0,stream>>>(ws, w1, w2, ln, x, wk, wv, wq);
  p1a<<<dim3(32,8,3),256,0,stream>>>(ws);
  p1b<<<2048,256,0,stream>>>(x, kn, qn, aw, tw, ew, ws);
  tr_k<<<dim3(8,8,4),256,0,stream>>>(ws);
  for(int c=0;c<=16;c++){
    k1_w1<<<dim3(65,4),256,0,stream>>>(ws, c);
    k2_w2<<<dim3(32,4),256,0,stream>>>(ws, c);
    if(c<16){
      k3_rms<<<dim3(32,4),256,0,stream>>>(ws, c);
      k4_dh<<<dim3(64,4),256,0,stream>>>(ws, c);
    }
  }
  r1_gemm<<<dim3(8,16,4),256,0,stream>>>(ws);
  r2_gemm<<<dim3(8,8,4),256,0,stream>>>(ws);
  r3_out<<<2048,256,0,stream>>>(ws, d_out);
}